// Round 5
// baseline (2317.393 us; speedup 1.0000x reference)
//
#include <hip/hip_runtime.h>

typedef unsigned short ushort;
typedef __attribute__((ext_vector_type(8))) short short8;
typedef __attribute__((ext_vector_type(4))) short short4v;
typedef __attribute__((ext_vector_type(4))) float f32x4;

#define Bb 2
#define Tt 2048
#define Dd 2048
#define Hh 16
#define Mm 4096                 // B*T
#define MD 8388608u             // Mm*Dd

__device__ __forceinline__ float b2f(ushort u) {
  union { unsigned int ui; float f; } v; v.ui = ((unsigned int)u) << 16; return v.f;
}
__device__ __forceinline__ ushort f2b(float f) {
  union { float f; unsigned int u; } v; v.f = f;
  unsigned int r = (v.u + 0x7fffu + ((v.u >> 16) & 1u)) >> 16;
  return (ushort)r;
}
__device__ __forceinline__ void split3(float v, ushort& s0, ushort& s1, ushort& s2) {
  ushort a = f2b(v);        float f0 = b2f(a);
  float r1 = v - f0;        ushort b = f2b(r1);  float f1 = b2f(b);
  float r2 = r1 - f1;       ushort c = f2b(r2);
  s0 = a; s1 = b; s2 = c;
}
// RTZ hi + exact residual chain: same fp32-grade accuracy (residuals are exact), ~2.5x fewer VALU ops
__device__ __forceinline__ void split3_rtz(float v, ushort& s0, ushort& s1, ushort& s2) {
  union { float f; unsigned u; } c; c.f = v;
  s0 = (ushort)(c.u >> 16);
  union { unsigned u; float f; } h; h.u = c.u & 0xffff0000u;
  float r1 = v - h.f;                       // exact
  union { float f; unsigned u; } c1; c1.f = r1;
  s1 = (ushort)(c1.u >> 16);
  union { unsigned u; float f; } h1; h1.u = c1.u & 0xffff0000u;
  float r2 = r1 - h1.f;                     // exact
  s2 = f2b(r2);
}
__device__ __forceinline__ float softplusf(float x) {
  return fmaxf(x, 0.f) + log1pf(expf(-fabsf(x)));
}
__device__ __forceinline__ short4v tr16(unsigned a) {
  short4v d;
  asm volatile("ds_read_b64_tr_b16 %0, %1" : "=v"(d) : "v"(a));
  return d;
}

// ---------------- x -> 3 bf16 split planes (row-major, no transpose) ----------------
__global__ __launch_bounds__(256) void xsplit_k(const float* __restrict__ x,
                                                ushort* __restrict__ S0,
                                                ushort* __restrict__ S1,
                                                ushort* __restrict__ S2) {
  size_t i = ((size_t)blockIdx.x * 256 + threadIdx.x) * 8;
  float v[8];
  *(float4*)&v[0] = *(const float4*)(x + i);
  *(float4*)&v[4] = *(const float4*)(x + i + 4);
  ushort h0[8], h1[8], h2[8];
#pragma unroll
  for (int j = 0; j < 8; ++j) split3_rtz(v[j], h0[j], h1[j], h2[j]);
  *(uint4*)(S0 + i) = *(uint4*)h0;
  *(uint4*)(S1 + i) = *(uint4*)h1;
  *(uint4*)(S2 + i) = *(uint4*)h2;
}

// ---------------- transpose one DxD fp32 matrix -> 3 bf16 split planes, transposed ----------------
__global__ __launch_bounds__(256) void split_transpose3(const float* __restrict__ W,
                                                        ushort* __restrict__ T0,
                                                        ushort* __restrict__ T1,
                                                        ushort* __restrict__ T2) {
  __shared__ float tile[64][68];
  int k0 = blockIdx.x << 6, n0 = blockIdx.y << 6;
  int r = threadIdx.x >> 2, c0 = (threadIdx.x & 3) << 4;
  const float* src = W + (size_t)(k0 + r) * Dd + n0 + c0;
#pragma unroll
  for (int q = 0; q < 4; ++q)
    *(float4*)&tile[r][c0 + 4 * q] = *(const float4*)(src + 4 * q);
  __syncthreads();
  ushort h0[16], h1[16], h2[16];
#pragma unroll
  for (int i = 0; i < 16; ++i) split3(tile[c0 + i][r], h0[i], h1[i], h2[i]);
  size_t o = (size_t)(n0 + r) * Dd + k0 + c0;
  *(uint4*)(T0 + o) = *(uint4*)&h0[0];  *(uint4*)(T0 + o + 8) = *(uint4*)&h0[8];
  *(uint4*)(T1 + o) = *(uint4*)&h1[0];  *(uint4*)(T1 + o + 8) = *(uint4*)&h1[8];
  *(uint4*)(T2 + o) = *(uint4*)&h2[0];  *(uint4*)(T2 + o + 8) = *(uint4*)&h2[8];
}

// ------------- 64x64-tile 6-term split-bf16 MFMA GEMM (fp32-grade): C = A(fp32) * Bt^T -------------
template <int BF16OUT>
__global__ __launch_bounds__(256) void gemm6(const float* __restrict__ A,
                                             const ushort* __restrict__ B0,
                                             const ushort* __restrict__ B1,
                                             const ushort* __restrict__ B2,
                                             void* __restrict__ CBase) {
  const int N = 2048, K = 2048;
  int m0 = blockIdx.y << 6, n0 = blockIdx.x << 6;
  __shared__ ushort As0[4096], As1[4096], As2[4096];
  __shared__ ushort Bs0[4096], Bs1[4096], Bs2[4096];
  int tid = threadIdx.x;
  int row = tid >> 2, c0 = (tid & 3) << 4;
  int sw = row & 7;
  int g0 = c0 >> 3;
  int dst0 = row * 64 + ((g0 ^ sw) << 3);
  int dst1 = row * 64 + (((g0 + 1) ^ sw) << 3);
  const float* aptr = A + (size_t)(m0 + row) * K + c0;
  const ushort* b0p = B0 + (size_t)(n0 + row) * K + c0;
  const ushort* b1p = B1 + (size_t)(n0 + row) * K + c0;
  const ushort* b2p = B2 + (size_t)(n0 + row) * K + c0;
  int lane = tid & 63, wave = tid >> 6;
  int l16 = lane & 15, quad = lane >> 4;
  int wm = (wave & 1) << 5, wn = (wave >> 1) << 5;
  f32x4 acc[2][2] = {};
  for (int k0 = 0; k0 < K; k0 += 64) {
    float av[16];
#pragma unroll
    for (int q = 0; q < 4; ++q)
      *(float4*)&av[4 * q] = *(const float4*)(aptr + k0 + 4 * q);
    ushort a0[16], a1[16], a2[16];
#pragma unroll
    for (int i = 0; i < 16; ++i) split3_rtz(av[i], a0[i], a1[i], a2[i]);
    uint4 b00 = *(const uint4*)(b0p + k0), b01 = *(const uint4*)(b0p + k0 + 8);
    uint4 b10 = *(const uint4*)(b1p + k0), b11 = *(const uint4*)(b1p + k0 + 8);
    uint4 b20 = *(const uint4*)(b2p + k0), b21 = *(const uint4*)(b2p + k0 + 8);
    *(uint4*)&As0[dst0] = *(uint4*)&a0[0];  *(uint4*)&As0[dst1] = *(uint4*)&a0[8];
    *(uint4*)&As1[dst0] = *(uint4*)&a1[0];  *(uint4*)&As1[dst1] = *(uint4*)&a1[8];
    *(uint4*)&As2[dst0] = *(uint4*)&a2[0];  *(uint4*)&As2[dst1] = *(uint4*)&a2[8];
    *(uint4*)&Bs0[dst0] = b00;  *(uint4*)&Bs0[dst1] = b01;
    *(uint4*)&Bs1[dst0] = b10;  *(uint4*)&Bs1[dst1] = b11;
    *(uint4*)&Bs2[dst0] = b20;  *(uint4*)&Bs2[dst1] = b21;
    __syncthreads();
#pragma unroll
    for (int kk = 0; kk < 2; ++kk) {
      short8 af0[2], af1[2], af2[2], bf0[2], bf1[2], bf2[2];
#pragma unroll
      for (int mi = 0; mi < 2; ++mi) {
        int rr = wm + (mi << 4) + l16;
        int g = (kk << 2) + quad;
        int idx = rr * 64 + ((g ^ (rr & 7)) << 3);
        af0[mi] = *(const short8*)&As0[idx];
        af1[mi] = *(const short8*)&As1[idx];
        af2[mi] = *(const short8*)&As2[idx];
      }
#pragma unroll
      for (int nj = 0; nj < 2; ++nj) {
        int rr = wn + (nj << 4) + l16;
        int g = (kk << 2) + quad;
        int idx = rr * 64 + ((g ^ (rr & 7)) << 3);
        bf0[nj] = *(const short8*)&Bs0[idx];
        bf1[nj] = *(const short8*)&Bs1[idx];
        bf2[nj] = *(const short8*)&Bs2[idx];
      }
#pragma unroll
      for (int mi = 0; mi < 2; ++mi)
#pragma unroll
        for (int nj = 0; nj < 2; ++nj) {
          // smallest-magnitude terms first for accuracy
          acc[mi][nj] = __builtin_amdgcn_mfma_f32_16x16x32_bf16(af2[mi], bf0[nj], acc[mi][nj], 0, 0, 0);
          acc[mi][nj] = __builtin_amdgcn_mfma_f32_16x16x32_bf16(af0[mi], bf2[nj], acc[mi][nj], 0, 0, 0);
          acc[mi][nj] = __builtin_amdgcn_mfma_f32_16x16x32_bf16(af1[mi], bf1[nj], acc[mi][nj], 0, 0, 0);
          acc[mi][nj] = __builtin_amdgcn_mfma_f32_16x16x32_bf16(af1[mi], bf0[nj], acc[mi][nj], 0, 0, 0);
          acc[mi][nj] = __builtin_amdgcn_mfma_f32_16x16x32_bf16(af0[mi], bf1[nj], acc[mi][nj], 0, 0, 0);
          acc[mi][nj] = __builtin_amdgcn_mfma_f32_16x16x32_bf16(af0[mi], bf0[nj], acc[mi][nj], 0, 0, 0);
        }
    }
    __syncthreads();
  }
#pragma unroll
  for (int mi = 0; mi < 2; ++mi)
#pragma unroll
    for (int nj = 0; nj < 2; ++nj)
#pragma unroll
      for (int r = 0; r < 4; ++r) {
        int mm = m0 + wm + (mi << 4) + (quad << 2) + r;
        int nn = n0 + wn + (nj << 4) + l16;
        float v = acc[mi][nj][r];
        if (BF16OUT)
          ((ushort*)CBase)[(size_t)mm * N + nn] = f2b(v);
        else
          ((float*)CBase)[(size_t)mm * N + nn] = v;
      }
}

// ------ 64x64-tile 6-term GEMM with PRE-SPLIT A (3 bf16 planes): pure-load staging ------
__global__ __launch_bounds__(256) void gemm_pre(const ushort* __restrict__ A0,
                                                const ushort* __restrict__ A1,
                                                const ushort* __restrict__ A2,
                                                const ushort* __restrict__ B0,
                                                const ushort* __restrict__ B1,
                                                const ushort* __restrict__ B2,
                                                float* __restrict__ C) {
  const int N = 2048, K = 2048;
  int m0 = blockIdx.y << 6, n0 = blockIdx.x << 6;
  __shared__ ushort As0[4096], As1[4096], As2[4096];
  __shared__ ushort Bs0[4096], Bs1[4096], Bs2[4096];
  int tid = threadIdx.x;
  int row = tid >> 2, c0 = (tid & 3) << 4;
  int sw = row & 7;
  int g0 = c0 >> 3;
  int dst0 = row * 64 + ((g0 ^ sw) << 3);
  int dst1 = row * 64 + (((g0 + 1) ^ sw) << 3);
  const ushort* a0p = A0 + (size_t)(m0 + row) * K + c0;
  const ushort* a1p = A1 + (size_t)(m0 + row) * K + c0;
  const ushort* a2p = A2 + (size_t)(m0 + row) * K + c0;
  const ushort* b0p = B0 + (size_t)(n0 + row) * K + c0;
  const ushort* b1p = B1 + (size_t)(n0 + row) * K + c0;
  const ushort* b2p = B2 + (size_t)(n0 + row) * K + c0;
  int lane = tid & 63, wave = tid >> 6;
  int l16 = lane & 15, quad = lane >> 4;
  int wm = (wave & 1) << 5, wn = (wave >> 1) << 5;
  f32x4 acc[2][2] = {};
  for (int k0 = 0; k0 < K; k0 += 64) {
    uint4 a00 = *(const uint4*)(a0p + k0), a01 = *(const uint4*)(a0p + k0 + 8);
    uint4 a10 = *(const uint4*)(a1p + k0), a11 = *(const uint4*)(a1p + k0 + 8);
    uint4 a20 = *(const uint4*)(a2p + k0), a21 = *(const uint4*)(a2p + k0 + 8);
    uint4 b00 = *(const uint4*)(b0p + k0), b01 = *(const uint4*)(b0p + k0 + 8);
    uint4 b10 = *(const uint4*)(b1p + k0), b11 = *(const uint4*)(b1p + k0 + 8);
    uint4 b20 = *(const uint4*)(b2p + k0), b21 = *(const uint4*)(b2p + k0 + 8);
    *(uint4*)&As0[dst0] = a00;  *(uint4*)&As0[dst1] = a01;
    *(uint4*)&As1[dst0] = a10;  *(uint4*)&As1[dst1] = a11;
    *(uint4*)&As2[dst0] = a20;  *(uint4*)&As2[dst1] = a21;
    *(uint4*)&Bs0[dst0] = b00;  *(uint4*)&Bs0[dst1] = b01;
    *(uint4*)&Bs1[dst0] = b10;  *(uint4*)&Bs1[dst1] = b11;
    *(uint4*)&Bs2[dst0] = b20;  *(uint4*)&Bs2[dst1] = b21;
    __syncthreads();
#pragma unroll
    for (int kk = 0; kk < 2; ++kk) {
      short8 af0[2], af1[2], af2[2], bf0[2], bf1[2], bf2[2];
#pragma unroll
      for (int mi = 0; mi < 2; ++mi) {
        int rr = wm + (mi << 4) + l16;
        int g = (kk << 2) + quad;
        int idx = rr * 64 + ((g ^ (rr & 7)) << 3);
        af0[mi] = *(const short8*)&As0[idx];
        af1[mi] = *(const short8*)&As1[idx];
        af2[mi] = *(const short8*)&As2[idx];
      }
#pragma unroll
      for (int nj = 0; nj < 2; ++nj) {
        int rr = wn + (nj << 4) + l16;
        int g = (kk << 2) + quad;
        int idx = rr * 64 + ((g ^ (rr & 7)) << 3);
        bf0[nj] = *(const short8*)&Bs0[idx];
        bf1[nj] = *(const short8*)&Bs1[idx];
        bf2[nj] = *(const short8*)&Bs2[idx];
      }
#pragma unroll
      for (int mi = 0; mi < 2; ++mi)
#pragma unroll
        for (int nj = 0; nj < 2; ++nj) {
          acc[mi][nj] = __builtin_amdgcn_mfma_f32_16x16x32_bf16(af2[mi], bf0[nj], acc[mi][nj], 0, 0, 0);
          acc[mi][nj] = __builtin_amdgcn_mfma_f32_16x16x32_bf16(af0[mi], bf2[nj], acc[mi][nj], 0, 0, 0);
          acc[mi][nj] = __builtin_amdgcn_mfma_f32_16x16x32_bf16(af1[mi], bf1[nj], acc[mi][nj], 0, 0, 0);
          acc[mi][nj] = __builtin_amdgcn_mfma_f32_16x16x32_bf16(af1[mi], bf0[nj], acc[mi][nj], 0, 0, 0);
          acc[mi][nj] = __builtin_amdgcn_mfma_f32_16x16x32_bf16(af0[mi], bf1[nj], acc[mi][nj], 0, 0, 0);
          acc[mi][nj] = __builtin_amdgcn_mfma_f32_16x16x32_bf16(af0[mi], bf0[nj], acc[mi][nj], 0, 0, 0);
        }
    }
    __syncthreads();
  }
#pragma unroll
  for (int mi = 0; mi < 2; ++mi)
#pragma unroll
    for (int nj = 0; nj < 2; ++nj)
#pragma unroll
      for (int r = 0; r < 4; ++r) {
        int mm = m0 + wm + (mi << 4) + (quad << 2) + r;
        int nn = n0 + wn + (nj << 4) + l16;
        C[(size_t)mm * N + nn] = acc[mi][nj][r];
      }
}

// ---------------- 64x64-tile bf16-A x bf16-B GEMM (final projection), fp32 out ----------------
__global__ __launch_bounds__(256) void gemm_b16A(const ushort* __restrict__ A,
                                                 const ushort* __restrict__ Bt,
                                                 float* __restrict__ C) {
  const int N = 2048, K = 2048;
  int m0 = blockIdx.y << 6, n0 = blockIdx.x << 6;
  __shared__ ushort As[64 * 64];
  __shared__ ushort Bs[64 * 64];
  int tid = threadIdx.x;
  int row = tid >> 2, c0 = (tid & 3) << 4;
  int sw = row & 7;
  int g0 = c0 >> 3;
  int dst0 = row * 64 + ((g0 ^ sw) << 3);
  int dst1 = row * 64 + (((g0 + 1) ^ sw) << 3);
  const ushort* aptr = A + (size_t)(m0 + row) * K + c0;
  const ushort* bptr = Bt + (size_t)(n0 + row) * K + c0;
  int lane = tid & 63, wave = tid >> 6;
  int l16 = lane & 15, quad = lane >> 4;
  int wm = (wave & 1) << 5, wn = (wave >> 1) << 5;
  f32x4 acc[2][2] = {};
  for (int k0 = 0; k0 < K; k0 += 64) {
    uint4 av0 = *(const uint4*)(aptr + k0);
    uint4 av1 = *(const uint4*)(aptr + k0 + 8);
    uint4 bv0 = *(const uint4*)(bptr + k0);
    uint4 bv1 = *(const uint4*)(bptr + k0 + 8);
    *(uint4*)&As[dst0] = av0;
    *(uint4*)&As[dst1] = av1;
    *(uint4*)&Bs[dst0] = bv0;
    *(uint4*)&Bs[dst1] = bv1;
    __syncthreads();
#pragma unroll
    for (int kk = 0; kk < 2; ++kk) {
      short8 af[2], bf[2];
#pragma unroll
      for (int mi = 0; mi < 2; ++mi) {
        int rr = wm + (mi << 4) + l16;
        int g = (kk << 2) + quad;
        af[mi] = *(const short8*)&As[rr * 64 + ((g ^ (rr & 7)) << 3)];
      }
#pragma unroll
      for (int nj = 0; nj < 2; ++nj) {
        int rr = wn + (nj << 4) + l16;
        int g = (kk << 2) + quad;
        bf[nj] = *(const short8*)&Bs[rr * 64 + ((g ^ (rr & 7)) << 3)];
      }
#pragma unroll
      for (int mi = 0; mi < 2; ++mi)
#pragma unroll
        for (int nj = 0; nj < 2; ++nj)
          acc[mi][nj] = __builtin_amdgcn_mfma_f32_16x16x32_bf16(af[mi], bf[nj], acc[mi][nj], 0, 0, 0);
    }
    __syncthreads();
  }
#pragma unroll
  for (int mi = 0; mi < 2; ++mi)
#pragma unroll
    for (int nj = 0; nj < 2; ++nj)
#pragma unroll
      for (int r = 0; r < 4; ++r) {
        int mm = m0 + wm + (mi << 4) + (quad << 2) + r;
        int nn = n0 + wn + (nj << 4) + l16;
        C[(size_t)mm * N + nn] = acc[mi][nj][r];
      }
}

// ---------------- clock pre-activation: x @ W_clock (2048x16), fp32 ----------------
__global__ __launch_bounds__(64) void wclock_k(const float* __restrict__ x,
                                               const float* __restrict__ Wc,
                                               float* __restrict__ out) {
  int m = blockIdx.x, lane = threadIdx.x;
  const float* xr = x + (size_t)m * Dd;
  float acc[16];
#pragma unroll
  for (int h = 0; h < 16; ++h) acc[h] = 0.f;
  for (int k = lane; k < Dd; k += 64) {
    float xv = xr[k];
    const float* wr = Wc + k * 16;
#pragma unroll
    for (int h = 0; h < 16; ++h) acc[h] += xv * wr[h];
  }
#pragma unroll
  for (int h = 0; h < 16; ++h) {
#pragma unroll
    for (int off = 32; off; off >>= 1) acc[h] += __shfl_down(acc[h], off);
  }
  if (lane == 0) {
    float* o = out + (size_t)m * 16;
#pragma unroll
    for (int h = 0; h < 16; ++h) o[h] = acc[h];
  }
}

// ---------------- per-chunk max of p = (x@W_p) + log(clock) over 256-t chunks ----------------
__global__ __launch_bounds__(128) void pmaxchunk_k(const float* __restrict__ Pf,
                                                   const float* __restrict__ cpre,
                                                   float* __restrict__ pmaxc) {
  int bh = blockIdx.x, ch = blockIdx.y, d = threadIdx.x;
  int b = bh >> 4, h = bh & 15;
  float mx = -1e30f;
  int t0 = ch << 8;
  for (int t = t0; t < t0 + 256; ++t) {
    float pr = Pf[((size_t)(b * Tt + t)) * Dd + h * 128 + d];
    float c = softplusf(cpre[(b * Tt + t) * Hh + h]) + 1e-6f;
    mx = fmaxf(mx, pr + logf(c));
  }
  pmaxc[(size_t)(bh * 8 + ch) * 128 + d] = mx;
}

// ======== blocked scan, stage 1: elementwise (rope, pe, gj, clock) + per-32t chunk sums ========
__global__ __launch_bounds__(128) void scan_ew_k(float* planes,
                                                 const float* __restrict__ cpre,
                                                 const float* __restrict__ pmaxc,
                                                 float* __restrict__ clockv,
                                                 float* __restrict__ sum_pe,
                                                 float* __restrict__ sum_gj,
                                                 float* __restrict__ sum_ck) {
  int ch = blockIdx.x, bh = blockIdx.y;
  int b = bh >> 4, h = bh & 15, d = threadIdx.x;
  float* Qf = planes;
  float* Kf = planes + (size_t)MD;
  float* Gf = planes + 2 * (size_t)MD;
  float* Pf = planes + 3 * (size_t)MD;
  float invf = (float)exp(-((double)((d & 63) * 2) / 128.0) * log(10000.0));
  float pmax = -1e30f;
#pragma unroll
  for (int c = 0; c < 8; ++c) pmax = fmaxf(pmax, pmaxc[(size_t)(bh * 8 + c) * 128 + d]);
  float s_pe = 0.f, s_gj = 0.f, s_ck = 0.f;
  int t0 = ch << 5;
#pragma unroll 4
  for (int i = 0; i < 32; ++i) {
    int t = t0 + i;
    size_t off = ((size_t)(b * Tt + t)) * Dd + h * 128 + d;
    float qv = Qf[off], kv = Kf[off], pv = Pf[off], gv = Gf[off];
    float clock = softplusf(cpre[(b * Tt + t) * Hh + h]) + 1e-6f;
    float ang = (float)t * invf;
    float c_ = cosf(ang), s_ = sinf(ang);
    float qp = __shfl_xor(qv, 1);
    float kp = __shfl_xor(kv, 1);
    float qrot = (d & 1) ? qp : -qp;
    float krot = (d & 1) ? kp : -kp;
    float qr = qv * c_ + qrot * s_;
    float kr = kv * c_ + krot * s_;
    float pe = expf(pv + logf(clock) - pmax);
    s_pe += pe;
    float gj = -softplusf(gv) * clock;
    s_gj += gj;
    Qf[off] = qr;
    Kf[off] = kr;
    Gf[off] = gj;     // gj for now; scan_apply_k turns it into e
    Pf[off] = pe;
    if (d == 0) {
      clockv[bh * Tt + t] = clock;
      s_ck += clock;
    }
  }
  size_t so = (size_t)(bh * 64 + ch) * 128 + d;
  sum_pe[so] = s_pe;
  sum_gj[so] = s_gj;
  if (d == 0) sum_ck[bh * 64 + ch] = s_ck;
}

// ======== blocked scan, stage 2: exclusive scan of chunk sums (pcs_cp falls out directly) ========
__global__ __launch_bounds__(128) void scan_off_k(const float* __restrict__ sum_pe,
                                                  const float* __restrict__ sum_gj,
                                                  const float* __restrict__ sum_ck,
                                                  float* __restrict__ pcs_cp,
                                                  float* __restrict__ goff,
                                                  float* __restrict__ coff) {
  int bh = blockIdx.x, d = threadIdx.x;
  float ppe = 0.f, pgj = 0.f, pck = 0.f;
  for (int c = 0; c < 64; ++c) {
    size_t o = (size_t)(bh * 64 + c) * 128 + d;
    pcs_cp[o] = ppe;
    goff[o] = pgj;
    ppe += sum_pe[o];
    pgj += sum_gj[o];
    if (d == 0) { coff[bh * 64 + c] = pck; pck += sum_ck[bh * 64 + c]; }
  }
}

// ======== blocked scan, stage 3: within-chunk gcs -> e (Gf), and ccsv ========
__global__ __launch_bounds__(128) void scan_apply_k(float* planes,
                                                    const float* __restrict__ goff,
                                                    const float* __restrict__ coff,
                                                    const float* __restrict__ clockv,
                                                    float* __restrict__ ccsv) {
  int ch = blockIdx.x, bh = blockIdx.y;
  int b = bh >> 4, h = bh & 15, d = threadIdx.x;
  float* Gf = planes + 2 * (size_t)MD;
  float g = goff[(size_t)(bh * 64 + ch) * 128 + d];
  float ccs = (d == 0) ? coff[bh * 64 + ch] : 0.f;
  int t0 = ch << 5;
#pragma unroll 4
  for (int i = 0; i < 32; ++i) {
    int t = t0 + i;
    size_t off = ((size_t)(b * Tt + t)) * Dd + h * 128 + d;
    float gj = Gf[off];
    g += gj;
    float e = expf(fminf(fmaxf(g, -50.f), 40.f));
    Gf[off] = e;
    if (d == 0) {
      ccs += clockv[bh * Tt + t];
      ccsv[bh * Tt + t] = ccs;
    }
  }
}

// ---------------- MFMA flash attention: 128 q-rows/block, 8 waves x 16 rows ----------------
// QK^T via 2-term split-bf16 MFMA; PV via MFMA with hi/lo split P and tr-read V fragments.
// K re-staged 16x (vs 32x at 64-row blocks); 16 waves/CU occupancy.
__global__ __launch_bounds__(512, 2) void attn_mfma_k(const float* __restrict__ planes,
                                                      const ushort* __restrict__ Vb,
                                                      const float* __restrict__ clockv,
                                                      const float* __restrict__ ccsv,
                                                      const float* __restrict__ pcs_cp,
                                                      ushort* __restrict__ attnout) {
  __shared__ float smemf[18432];            // 72 KB -> 2 blocks/CU, 16 waves/CU
  ushort* Khi = (ushort*)smemf;             // [32 keys][384 dims] swizzled  @0      (24576 B)
  ushort* Klo = Khi + 12288;                //                              @24576  (24576 B)
  ushort* Vsm = Khi + 24576;                // [32 keys][128 dims] 4x16-subtiled @49152 (8192 B)
  unsigned* Pu = (unsigned*)(smemf + 14336);// 8 waves x [16 rows][32 keys] u32 @57344 (16384 B)
  float* pcsL = smemf;                      // phase alias @0: [64][128] f32 (32 KB)
  ushort* qscr = (ushort*)(smemf + 8192);   // phase alias @32768: 4 x 8 KB

  int tid = threadIdx.x;
  int lane = tid & 63, wave = tid >> 6;     // wave 0..7
  int l15 = lane & 15, qd = lane >> 4;
  int qt0 = blockIdx.x << 7;                // 128 q rows per block
  int bh = blockIdx.y, b = bh >> 4, h = bh & 15;
  const float* Qf = planes;
  const float* Kf = planes + (size_t)MD;
  const float* Ef = planes + 2 * (size_t)MD;
  const float* Pe = planes + 3 * (size_t)MD;
  size_t pbase = ((size_t)b * Tt) * Dd + h * 128;

  // ---- Q prep in 2 rounds: rows 0..63 (waves 0..3), rows 64..127 (waves 4..7) ----
  short8 qh[12], ql[12];
  int wl = wave & 3;
  int rloc = lane >> 2;                     // 0..15, row within wave tile
  {
    ushort* sh = qscr + (wl << 12);         // [16][128] hi ushort (4 KB)
    ushort* sl = sh + 2048;                 // lo (4 KB)
#pragma unroll
    for (int rd = 0; rd < 2; ++rd) {
      // phase A: pcs replay for this round's 64 rows (256 threads; chunk==32 rows)
      if (tid < 256) {
        int d = tid & 127, seg = tid >> 7;
        int rbase = (rd << 6) + (seg << 5);
        float pcs = pcs_cp[((size_t)bh * 64 + (qt0 >> 5) + (rd << 1) + seg) * 128 + d];
        for (int i = 0; i < 32; ++i) {
          pcs += Pe[pbase + (size_t)(qt0 + rbase + i) * Dd + d];
          pcsL[((seg << 5) + i) * 128 + d] = pcs;
        }
      }
      __syncthreads();
      int part = ((wave >> 2) == rd);
      int grow = qt0 + (rd << 6) + (wl << 4) + rloc;
      float ccsr = __builtin_amdgcn_rcpf(ccsv[bh * Tt + grow]);
      size_t goffq = pbase + (size_t)grow * Dd;
#pragma unroll
      for (int cd = 0; cd < 3; ++cd) {
        __syncthreads();
        if (part) {
#pragma unroll
          for (int j = 0; j < 4; ++j) {
            int d0 = ((lane & 3) << 5) + (j << 3);   // 8 dims
            float qv[8], mv[8];
            *(float4*)&qv[0] = *(const float4*)(Qf + goffq + d0);
            *(float4*)&qv[4] = *(const float4*)(Qf + goffq + d0 + 4);
            if (cd == 0) {
              *(float4*)&mv[0] = *(const float4*)&pcsL[((wl << 4) + rloc) * 128 + d0];
              *(float4*)&mv[4] = *(const float4*)&pcsL[((wl << 4) + rloc) * 128 + d0 + 4];
#pragma unroll
              for (int i = 0; i < 8; ++i) qv[i] = qv[i] * __builtin_amdgcn_rcpf(mv[i] + 1e-8f);
            } else if (cd == 1) {
              *(float4*)&mv[0] = *(const float4*)(Ef + goffq + d0);
              *(float4*)&mv[4] = *(const float4*)(Ef + goffq + d0 + 4);
#pragma unroll
              for (int i = 0; i < 8; ++i) qv[i] = qv[i] * mv[i];
            } else {
#pragma unroll
              for (int i = 0; i < 8; ++i) qv[i] = qv[i] * ccsr;
            }
            ushort hi8[8], lo8[8];
#pragma unroll
            for (int i = 0; i < 8; ++i) {
              ushort a = f2b(qv[i]); hi8[i] = a; lo8[i] = f2b(qv[i] - b2f(a));
            }
            int g = ((lane & 3) << 2) + j;          // dim group 0..15
            int phys = (g & 8) | ((g ^ rloc) & 7);
            *(uint4*)&sh[rloc * 128 + (phys << 3)] = *(uint4*)hi8;
            *(uint4*)&sl[rloc * 128 + (phys << 3)] = *(uint4*)lo8;
          }
        }
        __syncthreads();
        if (part) {
#pragma unroll
          for (int ksl = 0; ksl < 4; ++ksl) {
            int g = (ksl << 2) + qd;
            int phys = (g & 8) | ((g ^ l15) & 7);
            qh[(cd << 2) + ksl] = *(const short8*)&sh[l15 * 128 + (phys << 3)];
            ql[(cd << 2) + ksl] = *(const short8*)&sl[l15 * 128 + (phys << 3)];
          }
        }
      }
      __syncthreads();                      // pcsL/qscr reuse (and Khi alias) safe
    }
  }

  // ---- main loop over 64 key-tiles of 32 ----
  float mi4[4], li4[4];
  f32x4 acc_pv[8] = {};
#pragma unroll
  for (int r = 0; r < 4; ++r) { mi4[r] = -1e30f; li4[r] = 0.f; }
  const float scl = 0.05103103630798287f;   // 1/sqrt(384)
  const ushort* vbase = Vb + pbase;
  unsigned* PuW = Pu + (wave << 9);         // per-wave 2 KB
  unsigned VsmA = (unsigned)(size_t)Vsm;    // LDS byte address (low 32 bits of flat)
  int kk = tid >> 4;                        // key 0..31 (staging role)
  int kdb = tid & 15;                       // 8-dim block (staging role)

  for (int st = 0; st < 64; ++st) {
    int s0 = st << 5;
    __syncthreads();                        // all reads of K/V tile (st-1) done
    // ---- stage K (3 cat slots, RTZ-hi + exact-residual-lo split) + V tile (4x16 subtiles) ----
    {
      size_t roff = pbase + (size_t)(s0 + kk) * Dd + (kdb << 3);
      float ck = clockv[bh * Tt + s0 + kk];
      float kv[8], pev[8], ev[8];
      *(float4*)&kv[0] = *(const float4*)(Kf + roff);
      *(float4*)&kv[4] = *(const float4*)(Kf + roff + 4);
      *(float4*)&pev[0] = *(const float4*)(Pe + roff);
      *(float4*)&pev[4] = *(const float4*)(Pe + roff + 4);
      *(float4*)&ev[0] = *(const float4*)(Ef + roff);
      *(float4*)&ev[4] = *(const float4*)(Ef + roff + 4);
#pragma unroll
      for (int slot = 0; slot < 3; ++slot) {
        float val[8];
        if (slot == 0) {
#pragma unroll
          for (int i = 0; i < 8; ++i) val[i] = kv[i] * pev[i];
        } else if (slot == 1) {
#pragma unroll
          for (int i = 0; i < 8; ++i) val[i] = kv[i] * __builtin_amdgcn_rcpf(ev[i] + 1e-8f);
        } else {
#pragma unroll
          for (int i = 0; i < 8; ++i) val[i] = kv[i] * ck;
        }
        unsigned ub[8], ul[8];
#pragma unroll
        for (int i = 0; i < 8; ++i) {
          union { float f; unsigned u; } c; c.f = val[i];
          ub[i] = c.u;
          union { unsigned u; float f; } hm; hm.u = c.u & 0xffff0000u;
          union { float f; unsigned u; } lr; lr.f = val[i] - hm.f;
          ul[i] = lr.u;
        }
        uint4 hi4, lo4;
        hi4.x = (ub[0] >> 16) | (ub[1] & 0xffff0000u);
        hi4.y = (ub[2] >> 16) | (ub[3] & 0xffff0000u);
        hi4.z = (ub[4] >> 16) | (ub[5] & 0xffff0000u);
        hi4.w = (ub[6] >> 16) | (ub[7] & 0xffff0000u);
        lo4.x = (ul[0] >> 16) | (ul[1] & 0xffff0000u);
        lo4.y = (ul[2] >> 16) | (ul[3] & 0xffff0000u);
        lo4.z = (ul[4] >> 16) | (ul[5] & 0xffff0000u);
        lo4.w = (ul[6] >> 16) | (ul[7] & 0xffff0000u);
        int g = (slot << 4) + kdb;
        int phys = (g & ~7) | ((g ^ kk) & 7);
        *(uint4*)&Khi[kk * 384 + (phys << 3)] = hi4;
        *(uint4*)&Klo[kk * 384 + (phys << 3)] = lo4;
      }
      // V: subtile layout: byte = chunk*1024 + (m&1)*512 + (m>>1)*128 + (key&3)*32 + half*16
      const ushort* vsrc = vbase + (size_t)(s0 + kk) * Dd + (kdb << 3);
      int vbyte = ((kdb >> 1) << 10) + (((kk >> 2) & 1) << 9) + ((kk >> 3) << 7) +
                  ((kk & 3) << 5) + ((kdb & 1) << 4);
      *(uint4*)((char*)Vsm + vbyte) = *(const uint4*)vsrc;
    }
    __syncthreads();
    // ---- QK^T: 2-term split-bf16 MFMA (3 terms, smallest first) ----
    f32x4 acc0 = {}, acc1 = {};
#pragma unroll
    for (int ks = 0; ks < 12; ++ks) {
      int g = (ks << 2) + qd;
      int p0i = (g & ~7) | ((g ^ l15) & 7);
      int p1i = (g & ~7) | ((g ^ (16 + l15)) & 7);
      short8 b0h = *(const short8*)&Khi[l15 * 384 + (p0i << 3)];
      short8 b0l = *(const short8*)&Klo[l15 * 384 + (p0i << 3)];
      short8 b1h = *(const short8*)&Khi[(16 + l15) * 384 + (p1i << 3)];
      short8 b1l = *(const short8*)&Klo[(16 + l15) * 384 + (p1i << 3)];
      acc0 = __builtin_amdgcn_mfma_f32_16x16x32_bf16(ql[ks], b0h, acc0, 0, 0, 0);
      acc0 = __builtin_amdgcn_mfma_f32_16x16x32_bf16(qh[ks], b0l, acc0, 0, 0, 0);
      acc0 = __builtin_amdgcn_mfma_f32_16x16x32_bf16(qh[ks], b0h, acc0, 0, 0, 0);
      acc1 = __builtin_amdgcn_mfma_f32_16x16x32_bf16(ql[ks], b1h, acc1, 0, 0, 0);
      acc1 = __builtin_amdgcn_mfma_f32_16x16x32_bf16(qh[ks], b1l, acc1, 0, 0, 0);
      acc1 = __builtin_amdgcn_mfma_f32_16x16x32_bf16(qh[ks], b1h, acc1, 0, 0, 0);
    }
    // ---- online softmax (rows = qd*4+r, cols = keys via l15); P -> Pu (hi/lo packed) ----
#pragma unroll
    for (int r = 0; r < 4; ++r) {
      float sa = acc0[r] * scl, sb = acc1[r] * scl;
      float mx = fmaxf(sa, sb);
#pragma unroll
      for (int m = 1; m < 16; m <<= 1) mx = fmaxf(mx, __shfl_xor(mx, m));
      float mn = fmaxf(mi4[r], mx);
      float al = expf(mi4[r] - mn);
      float p0 = expf(sa - mn), p1 = expf(sb - mn);
      float rs = p0 + p1;
#pragma unroll
      for (int m = 1; m < 16; m <<= 1) rs += __shfl_xor(rs, m);
      li4[r] = li4[r] * al + rs;
      mi4[r] = mn;
#pragma unroll
      for (int n0 = 0; n0 < 8; ++n0) acc_pv[n0][r] *= al;
      int R = (qd << 2) + r;
      {
        union { float f; unsigned u; } c0, c1; c0.f = p0; c1.f = p1;
        union { unsigned u; float f; } m0_, m1_;
        m0_.u = c0.u & 0xffff0000u; m1_.u = c1.u & 0xffff0000u;
        union { float f; unsigned u; } d0_, d1_;
        d0_.f = p0 - m0_.f; d1_.f = p1 - m1_.f;
        unsigned u0 = (c0.u >> 16) | (d0_.u & 0xffff0000u);
        unsigned u1 = (c1.u >> 16) | (d1_.u & 0xffff0000u);
        int r7 = R & 7;
        char* pb = (char*)PuW + (R << 7) + ((l15 & 3) << 2);
        *(unsigned*)(pb + (((l15 >> 2) ^ r7) << 4)) = u0;
        *(unsigned*)(pb + ((((l15 >> 2) + 4) ^ r7) << 4)) = u1;
      }
    }
    // ---- PV via MFMA: A = P hi/lo fragments (wave-private Pu), B = V tr-read fragments ----
    {
      unsigned pw[8];
      {
        const char* pb = (const char*)PuW + l15 * 128;
        uint4 w0 = *(const uint4*)(pb + ((((qd << 1)) ^ (l15 & 7)) << 4));
        uint4 w1 = *(const uint4*)(pb + ((((qd << 1) | 1) ^ (l15 & 7)) << 4));
        pw[0] = w0.x; pw[1] = w0.y; pw[2] = w0.z; pw[3] = w0.w;
        pw[4] = w1.x; pw[5] = w1.y; pw[6] = w1.z; pw[7] = w1.w;
      }
      union { unsigned u[4]; short8 s; } uph, upl;
#pragma unroll
      for (int i = 0; i < 4; ++i) {
        uph.u[i] = (pw[2 * i] & 0xffffu) | (pw[2 * i + 1] << 16);
        upl.u[i] = (pw[2 * i] >> 16) | (pw[2 * i + 1] & 0xffff0000u);
      }
      short4v tv[16];
#pragma unroll
      for (int n0 = 0; n0 < 8; ++n0) {
        unsigned a0 = VsmA + (n0 << 10) + (lane << 3);
        tv[2 * n0] = tr16(a0);              // keys qd*8 .. +3 at dim col l15
        tv[2 * n0 + 1] = tr16(a0 + 512);    // keys qd*8+4 .. +7
      }
      asm volatile("s_waitcnt lgkmcnt(0)" ::: "memory");
      __builtin_amdgcn_sched_barrier(0);
#pragma unroll
      for (int n0 = 0; n0 < 8; ++n0) {
        short8 bv = __builtin_shufflevector(tv[2 * n0], tv[2 * n0 + 1], 0, 1, 2, 3, 4, 5, 6, 7);
        acc_pv[n0] = __builtin_amdgcn_mfma_f32_16x16x32_bf16(uph.s, bv, acc_pv[n0], 0, 0, 0);
        acc_pv[n0] = __builtin_amdgcn_mfma_f32_16x16x32_bf16(upl.s, bv, acc_pv[n0], 0, 0, 0);
      }
    }
  }
  // ---- epilogue: normalize, bf16 out (row = qd*4+r, dim = n0*16+l15) ----
#pragma unroll
  for (int r = 0; r < 4; ++r) {
    float inv = 1.f / li4[r];
    int trow = qt0 + (wave << 4) + (qd << 2) + r;
    ushort* orow = attnout + ((size_t)(b * Tt + trow)) * Dd + h * 128 + l15;
#pragma unroll
    for (int n0 = 0; n0 < 8; ++n0)
      orow[n0 << 4] = f2b(acc_pv[n0][r] * inv);
  }
}

extern "C" void kernel_launch(void* const* d_in, const int* in_sizes, int n_in,
                              void* d_out, int out_size, void* d_ws, size_t ws_size,
                              hipStream_t stream) {
  const float* x = (const float*)d_in[0];
  const float* Wq = (const float*)d_in[1];
  const float* Wk = (const float*)d_in[2];
  const float* Wv = (const float*)d_in[3];
  const float* Wg = (const float*)d_in[4];
  const float* Wp = (const float*)d_in[5];
  const float* Wclk = (const float*)d_in[6];
  const float* Wc = (const float*)d_in[7];

  // ---- workspace layout (~178 MiB) ----
  float* planes = (float*)d_ws;                       // 4 * MD fp32: qr | kr | e | pe
  float* Aq = planes;
  float* Bk = planes + (size_t)MD;
  float* Ce = planes + 2 * (size_t)MD;
  float* Dp = planes + 3 * (size_t)MD;
  ushort* Vb = (ushort*)(planes + 4 * (size_t)MD);    // MD bf16
  float* cpre = (float*)(Vb + (size_t)MD);            // 65536
  float* clockv = cpre + 65536;                       // 65536
  float* ccsv = clockv + 65536;                       // 65536
  float* pmaxc = ccsv + 65536;                        // 32768
  float* pcs_cp = pmaxc + 32768;                      // 32*64*128 = 262144
  ushort* Wt0 = (ushort*)(pcs_cp + 262144);           // 3 x Dd*Dd bf16 (projection phase)
  ushort* Wt1 = Wt0 + (size_t)Dd * Dd;
  ushort* Wt2 = Wt1 + (size_t)Dd * Dd;
  ushort* attnout = Wt0;                              // reuse Wt region (dead after projections)
  ushort* WcT0 = (ushort*)Ce;                         // post-attention: reuse e-plane for Wc^T
  ushort* WcT1 = WcT0 + (size_t)Dd * Dd;
  ushort* WcT2 = WcT1 + (size_t)Dd * Dd;
  // x-split planes (48 MB) live in Dp (32 MB) + Vb (16 MB) — dead until P/V projections,
  // which read x directly and run after all x-split consumers (stream-ordered).
  ushort* xs0 = (ushort*)Dp;                          // MD bf16
  ushort* xs1 = xs0 + (size_t)MD;                     // MD bf16
  ushort* xs2 = (ushort*)Vb;                          // MD bf16
  // scan temporaries live in the Wt2 region (dead during the scan phase; 3.2 MB << 8.4 MB)
  float* sum_pe = (float*)Wt2;                        // 262144
  float* sum_gj = sum_pe + 262144;                    // 262144
  float* goff_  = sum_gj + 262144;                    // 262144
  float* sum_ck = goff_ + 262144;                     // 2048
  float* coff_  = sum_ck + 2048;                      // 2048

  size_t needed = (size_t)((char*)(Wt2 + (size_t)Dd * Dd) - (char*)d_ws);
  if (ws_size < needed) return;  // diagnostic: absmax ~= 4.69 => ws too small

  dim3 tg(Dd / 64, Dd / 64), gg(Dd / 64, Mm / 64);

  // x split planes (once) — removes per-block re-splitting of A in Q/K/G projections
  xsplit_k<<<dim3(MD / 8 / 256), 256, 0, stream>>>(x, xs0, xs1, xs2);

  // Q, K, G projections: pre-split A (pure-load staging, MFMA-bound)
  split_transpose3<<<tg, 256, 0, stream>>>(Wq, Wt0, Wt1, Wt2);
  gemm_pre<<<gg, 256, 0, stream>>>(xs0, xs1, xs2, Wt0, Wt1, Wt2, Aq);
  split_transpose3<<<tg, 256, 0, stream>>>(Wk, Wt0, Wt1, Wt2);
  gemm_pre<<<gg, 256, 0, stream>>>(xs0, xs1, xs2, Wt0, Wt1, Wt2, Bk);
  split_transpose3<<<tg, 256, 0, stream>>>(Wg, Wt0, Wt1, Wt2);
  gemm_pre<<<gg, 256, 0, stream>>>(xs0, xs1, xs2, Wt0, Wt1, Wt2, Ce);
  // P, V projections: direct-x path (outputs overwrite the now-dead xs planes)
  split_transpose3<<<tg, 256, 0, stream>>>(Wp, Wt0, Wt1, Wt2);
  gemm6<0><<<gg, 256, 0, stream>>>(x, Wt0, Wt1, Wt2, (void*)Dp);
  split_transpose3<<<tg, 256, 0, stream>>>(Wv, Wt0, Wt1, Wt2);
  gemm6<1><<<gg, 256, 0, stream>>>(x, Wt0, Wt1, Wt2, (void*)Vb);

  // clock pre-activation, chunked p_max
  wclock_k<<<dim3(Mm), dim3(64), 0, stream>>>(x, Wclk, cpre);
  pmaxchunk_k<<<dim3(Bb * Hh, 8), dim3(128), 0, stream>>>(Dp, cpre, pmaxc);

  // blocked scan: elementwise+partials, chunk-offset scan, apply
  scan_ew_k<<<dim3(64, Bb * Hh), dim3(128), 0, stream>>>(planes, cpre, pmaxc, clockv,
                                                         sum_pe, sum_gj, sum_ck);
  scan_off_k<<<dim3(Bb * Hh), dim3(128), 0, stream>>>(sum_pe, sum_gj, sum_ck,
                                                      pcs_cp, goff_, coff_);
  scan_apply_k<<<dim3(64, Bb * Hh), dim3(128), 0, stream>>>(planes, goff_, coff_, clockv, ccsv);

  // MFMA flash attention -> attnout (bf16, in dead Wt region)
  attn_mfma_k<<<dim3(Tt / 128, Bb * Hh), dim3(512), 0, stream>>>(planes, Vb, clockv, ccsv, pcs_cp, attnout);

  // Wc^T (into dead e-plane), then final GEMM -> fp32 d_out
  split_transpose3<<<tg, 256, 0, stream>>>(Wc, WcT0, WcT1, WcT2);
  gemm_b16A<<<gg, 256, 0, stream>>>(attnout, WcT0, (float*)d_out);
}

// Round 6
// 1877.556 us; speedup vs baseline: 1.2343x; 1.2343x over previous
//
#include <hip/hip_runtime.h>

typedef unsigned short ushort;
typedef __attribute__((ext_vector_type(8))) short short8;
typedef __attribute__((ext_vector_type(4))) short short4v;
typedef __attribute__((ext_vector_type(4))) float f32x4;

#define Bb 2
#define Tt 2048
#define Dd 2048
#define Hh 16
#define Mm 4096                 // B*T
#define MD 8388608u             // Mm*Dd

__device__ __forceinline__ float b2f(ushort u) {
  union { unsigned int ui; float f; } v; v.ui = ((unsigned int)u) << 16; return v.f;
}
__device__ __forceinline__ ushort f2b(float f) {
  union { float f; unsigned int u; } v; v.f = f;
  unsigned int r = (v.u + 0x7fffu + ((v.u >> 16) & 1u)) >> 16;
  return (ushort)r;
}
__device__ __forceinline__ void split3(float v, ushort& s0, ushort& s1, ushort& s2) {
  ushort a = f2b(v);        float f0 = b2f(a);
  float r1 = v - f0;        ushort b = f2b(r1);  float f1 = b2f(b);
  float r2 = r1 - f1;       ushort c = f2b(r2);
  s0 = a; s1 = b; s2 = c;
}
// RTZ hi + exact residual chain: same fp32-grade accuracy (residuals are exact), ~2.5x fewer VALU ops
__device__ __forceinline__ void split3_rtz(float v, ushort& s0, ushort& s1, ushort& s2) {
  union { float f; unsigned u; } c; c.f = v;
  s0 = (ushort)(c.u >> 16);
  union { unsigned u; float f; } h; h.u = c.u & 0xffff0000u;
  float r1 = v - h.f;                       // exact
  union { float f; unsigned u; } c1; c1.f = r1;
  s1 = (ushort)(c1.u >> 16);
  union { unsigned u; float f; } h1; h1.u = c1.u & 0xffff0000u;
  float r2 = r1 - h1.f;                     // exact
  s2 = f2b(r2);
}
// 2-term split: RTZ hi + RNE residual (rep error ~2^-17 rel)
__device__ __forceinline__ void split2(float v, ushort& s0, ushort& s1) {
  union { float f; unsigned u; } c; c.f = v;
  s0 = (ushort)(c.u >> 16);
  union { unsigned u; float f; } h; h.u = c.u & 0xffff0000u;
  s1 = f2b(v - h.f);
}
__device__ __forceinline__ float softplusf(float x) {
  return fmaxf(x, 0.f) + log1pf(expf(-fabsf(x)));
}
__device__ __forceinline__ short4v tr16(unsigned a) {
  short4v d;
  asm volatile("ds_read_b64_tr_b16 %0, %1" : "=v"(d) : "v"(a));
  return d;
}

// ---------------- x -> 3 bf16 split planes (row-major, no transpose) ----------------
__global__ __launch_bounds__(256) void xsplit_k(const float* __restrict__ x,
                                                ushort* __restrict__ S0,
                                                ushort* __restrict__ S1,
                                                ushort* __restrict__ S2) {
  size_t i = ((size_t)blockIdx.x * 256 + threadIdx.x) * 8;
  float v[8];
  *(float4*)&v[0] = *(const float4*)(x + i);
  *(float4*)&v[4] = *(const float4*)(x + i + 4);
  ushort h0[8], h1[8], h2[8];
#pragma unroll
  for (int j = 0; j < 8; ++j) split3_rtz(v[j], h0[j], h1[j], h2[j]);
  *(uint4*)(S0 + i) = *(uint4*)h0;
  *(uint4*)(S1 + i) = *(uint4*)h1;
  *(uint4*)(S2 + i) = *(uint4*)h2;
}

// -------- transpose one DxD fp32 matrix -> NP bf16 split planes, transposed (NP=1,2,3) --------
template <int NP>
__global__ __launch_bounds__(256) void split_transposeN(const float* __restrict__ W,
                                                        ushort* __restrict__ T0,
                                                        ushort* __restrict__ T1,
                                                        ushort* __restrict__ T2) {
  __shared__ float tile[64][68];
  int k0 = blockIdx.x << 6, n0 = blockIdx.y << 6;
  int r = threadIdx.x >> 2, c0 = (threadIdx.x & 3) << 4;
  const float* src = W + (size_t)(k0 + r) * Dd + n0 + c0;
#pragma unroll
  for (int q = 0; q < 4; ++q)
    *(float4*)&tile[r][c0 + 4 * q] = *(const float4*)(src + 4 * q);
  __syncthreads();
  ushort h0[16], h1[16], h2[16];
#pragma unroll
  for (int i = 0; i < 16; ++i) {
    float v = tile[c0 + i][r];
    if (NP == 1) {
      h0[i] = f2b(v);
    } else if (NP == 2) {
      // RNE hi + RNE residual: rep err ~2^-18
      ushort a = f2b(v); h0[i] = a; h1[i] = f2b(v - b2f(a));
    } else {
      split3(v, h0[i], h1[i], h2[i]);
    }
  }
  size_t o = (size_t)(n0 + r) * Dd + k0 + c0;
  *(uint4*)(T0 + o) = *(uint4*)&h0[0];  *(uint4*)(T0 + o + 8) = *(uint4*)&h0[8];
  if (NP >= 2) { *(uint4*)(T1 + o) = *(uint4*)&h1[0];  *(uint4*)(T1 + o + 8) = *(uint4*)&h1[8]; }
  if (NP >= 3) { *(uint4*)(T2 + o) = *(uint4*)&h2[0];  *(uint4*)(T2 + o + 8) = *(uint4*)&h2[8]; }
}

// ------------- 64x64-tile 3-term split-bf16 MFMA GEMM: C = A(fp32) * Bt^T, ~2^-17 rel -------------
template <int BF16OUT>
__global__ __launch_bounds__(256) void gemm63(const float* __restrict__ A,
                                              const ushort* __restrict__ B0,
                                              const ushort* __restrict__ B1,
                                              void* __restrict__ CBase) {
  const int N = 2048, K = 2048;
  int m0 = blockIdx.y << 6, n0 = blockIdx.x << 6;
  __shared__ ushort As0[4096], As1[4096];
  __shared__ ushort Bs0[4096], Bs1[4096];
  int tid = threadIdx.x;
  int row = tid >> 2, c0 = (tid & 3) << 4;
  int sw = row & 7;
  int g0 = c0 >> 3;
  int dst0 = row * 64 + ((g0 ^ sw) << 3);
  int dst1 = row * 64 + (((g0 + 1) ^ sw) << 3);
  const float* aptr = A + (size_t)(m0 + row) * K + c0;
  const ushort* b0p = B0 + (size_t)(n0 + row) * K + c0;
  const ushort* b1p = B1 + (size_t)(n0 + row) * K + c0;
  int lane = tid & 63, wave = tid >> 6;
  int l16 = lane & 15, quad = lane >> 4;
  int wm = (wave & 1) << 5, wn = (wave >> 1) << 5;
  f32x4 acc[2][2] = {};
  for (int k0 = 0; k0 < K; k0 += 64) {
    float av[16];
#pragma unroll
    for (int q = 0; q < 4; ++q)
      *(float4*)&av[4 * q] = *(const float4*)(aptr + k0 + 4 * q);
    ushort a0[16], a1[16];
#pragma unroll
    for (int i = 0; i < 16; ++i) split2(av[i], a0[i], a1[i]);
    uint4 b00 = *(const uint4*)(b0p + k0), b01 = *(const uint4*)(b0p + k0 + 8);
    uint4 b10 = *(const uint4*)(b1p + k0), b11 = *(const uint4*)(b1p + k0 + 8);
    *(uint4*)&As0[dst0] = *(uint4*)&a0[0];  *(uint4*)&As0[dst1] = *(uint4*)&a0[8];
    *(uint4*)&As1[dst0] = *(uint4*)&a1[0];  *(uint4*)&As1[dst1] = *(uint4*)&a1[8];
    *(uint4*)&Bs0[dst0] = b00;  *(uint4*)&Bs0[dst1] = b01;
    *(uint4*)&Bs1[dst0] = b10;  *(uint4*)&Bs1[dst1] = b11;
    __syncthreads();
#pragma unroll
    for (int kk = 0; kk < 2; ++kk) {
      short8 af0[2], af1[2], bf0[2], bf1[2];
#pragma unroll
      for (int mi = 0; mi < 2; ++mi) {
        int rr = wm + (mi << 4) + l16;
        int g = (kk << 2) + quad;
        int idx = rr * 64 + ((g ^ (rr & 7)) << 3);
        af0[mi] = *(const short8*)&As0[idx];
        af1[mi] = *(const short8*)&As1[idx];
      }
#pragma unroll
      for (int nj = 0; nj < 2; ++nj) {
        int rr = wn + (nj << 4) + l16;
        int g = (kk << 2) + quad;
        int idx = rr * 64 + ((g ^ (rr & 7)) << 3);
        bf0[nj] = *(const short8*)&Bs0[idx];
        bf1[nj] = *(const short8*)&Bs1[idx];
      }
#pragma unroll
      for (int mi = 0; mi < 2; ++mi)
#pragma unroll
        for (int nj = 0; nj < 2; ++nj) {
          acc[mi][nj] = __builtin_amdgcn_mfma_f32_16x16x32_bf16(af1[mi], bf0[nj], acc[mi][nj], 0, 0, 0);
          acc[mi][nj] = __builtin_amdgcn_mfma_f32_16x16x32_bf16(af0[mi], bf1[nj], acc[mi][nj], 0, 0, 0);
          acc[mi][nj] = __builtin_amdgcn_mfma_f32_16x16x32_bf16(af0[mi], bf0[nj], acc[mi][nj], 0, 0, 0);
        }
    }
    __syncthreads();
  }
#pragma unroll
  for (int mi = 0; mi < 2; ++mi)
#pragma unroll
    for (int nj = 0; nj < 2; ++nj)
#pragma unroll
      for (int r = 0; r < 4; ++r) {
        int mm = m0 + wm + (mi << 4) + (quad << 2) + r;
        int nn = n0 + wn + (nj << 4) + l16;
        float v = acc[mi][nj][r];
        if (BF16OUT)
          ((ushort*)CBase)[(size_t)mm * N + nn] = f2b(v);
        else
          ((float*)CBase)[(size_t)mm * N + nn] = v;
      }
}

// ------ 64x64-tile 3-term GEMM with PRE-SPLIT A (2 bf16 planes): pure-load staging ------
__global__ __launch_bounds__(256) void gemm_pre3(const ushort* __restrict__ A0,
                                                 const ushort* __restrict__ A1,
                                                 const ushort* __restrict__ B0,
                                                 const ushort* __restrict__ B1,
                                                 float* __restrict__ C) {
  const int N = 2048, K = 2048;
  int m0 = blockIdx.y << 6, n0 = blockIdx.x << 6;
  __shared__ ushort As0[4096], As1[4096];
  __shared__ ushort Bs0[4096], Bs1[4096];
  int tid = threadIdx.x;
  int row = tid >> 2, c0 = (tid & 3) << 4;
  int sw = row & 7;
  int g0 = c0 >> 3;
  int dst0 = row * 64 + ((g0 ^ sw) << 3);
  int dst1 = row * 64 + (((g0 + 1) ^ sw) << 3);
  const ushort* a0p = A0 + (size_t)(m0 + row) * K + c0;
  const ushort* a1p = A1 + (size_t)(m0 + row) * K + c0;
  const ushort* b0p = B0 + (size_t)(n0 + row) * K + c0;
  const ushort* b1p = B1 + (size_t)(n0 + row) * K + c0;
  int lane = tid & 63, wave = tid >> 6;
  int l16 = lane & 15, quad = lane >> 4;
  int wm = (wave & 1) << 5, wn = (wave >> 1) << 5;
  f32x4 acc[2][2] = {};
  for (int k0 = 0; k0 < K; k0 += 64) {
    uint4 a00 = *(const uint4*)(a0p + k0), a01 = *(const uint4*)(a0p + k0 + 8);
    uint4 a10 = *(const uint4*)(a1p + k0), a11 = *(const uint4*)(a1p + k0 + 8);
    uint4 b00 = *(const uint4*)(b0p + k0), b01 = *(const uint4*)(b0p + k0 + 8);
    uint4 b10 = *(const uint4*)(b1p + k0), b11 = *(const uint4*)(b1p + k0 + 8);
    *(uint4*)&As0[dst0] = a00;  *(uint4*)&As0[dst1] = a01;
    *(uint4*)&As1[dst0] = a10;  *(uint4*)&As1[dst1] = a11;
    *(uint4*)&Bs0[dst0] = b00;  *(uint4*)&Bs0[dst1] = b01;
    *(uint4*)&Bs1[dst0] = b10;  *(uint4*)&Bs1[dst1] = b11;
    __syncthreads();
#pragma unroll
    for (int kk = 0; kk < 2; ++kk) {
      short8 af0[2], af1[2], bf0[2], bf1[2];
#pragma unroll
      for (int mi = 0; mi < 2; ++mi) {
        int rr = wm + (mi << 4) + l16;
        int g = (kk << 2) + quad;
        int idx = rr * 64 + ((g ^ (rr & 7)) << 3);
        af0[mi] = *(const short8*)&As0[idx];
        af1[mi] = *(const short8*)&As1[idx];
      }
#pragma unroll
      for (int nj = 0; nj < 2; ++nj) {
        int rr = wn + (nj << 4) + l16;
        int g = (kk << 2) + quad;
        int idx = rr * 64 + ((g ^ (rr & 7)) << 3);
        bf0[nj] = *(const short8*)&Bs0[idx];
        bf1[nj] = *(const short8*)&Bs1[idx];
      }
#pragma unroll
      for (int mi = 0; mi < 2; ++mi)
#pragma unroll
        for (int nj = 0; nj < 2; ++nj) {
          acc[mi][nj] = __builtin_amdgcn_mfma_f32_16x16x32_bf16(af1[mi], bf0[nj], acc[mi][nj], 0, 0, 0);
          acc[mi][nj] = __builtin_amdgcn_mfma_f32_16x16x32_bf16(af0[mi], bf1[nj], acc[mi][nj], 0, 0, 0);
          acc[mi][nj] = __builtin_amdgcn_mfma_f32_16x16x32_bf16(af0[mi], bf0[nj], acc[mi][nj], 0, 0, 0);
        }
    }
    __syncthreads();
  }
#pragma unroll
  for (int mi = 0; mi < 2; ++mi)
#pragma unroll
    for (int nj = 0; nj < 2; ++nj)
#pragma unroll
      for (int r = 0; r < 4; ++r) {
        int mm = m0 + wm + (mi << 4) + (quad << 2) + r;
        int nn = n0 + wn + (nj << 4) + l16;
        C[(size_t)mm * N + nn] = acc[mi][nj][r];
      }
}

// ------ 64x64-tile 6-term GEMM with PRE-SPLIT A (3 bf16 planes): pure-load staging (G only) ------
__global__ __launch_bounds__(256) void gemm_pre(const ushort* __restrict__ A0,
                                                const ushort* __restrict__ A1,
                                                const ushort* __restrict__ A2,
                                                const ushort* __restrict__ B0,
                                                const ushort* __restrict__ B1,
                                                const ushort* __restrict__ B2,
                                                float* __restrict__ C) {
  const int N = 2048, K = 2048;
  int m0 = blockIdx.y << 6, n0 = blockIdx.x << 6;
  __shared__ ushort As0[4096], As1[4096], As2[4096];
  __shared__ ushort Bs0[4096], Bs1[4096], Bs2[4096];
  int tid = threadIdx.x;
  int row = tid >> 2, c0 = (tid & 3) << 4;
  int sw = row & 7;
  int g0 = c0 >> 3;
  int dst0 = row * 64 + ((g0 ^ sw) << 3);
  int dst1 = row * 64 + (((g0 + 1) ^ sw) << 3);
  const ushort* a0p = A0 + (size_t)(m0 + row) * K + c0;
  const ushort* a1p = A1 + (size_t)(m0 + row) * K + c0;
  const ushort* a2p = A2 + (size_t)(m0 + row) * K + c0;
  const ushort* b0p = B0 + (size_t)(n0 + row) * K + c0;
  const ushort* b1p = B1 + (size_t)(n0 + row) * K + c0;
  const ushort* b2p = B2 + (size_t)(n0 + row) * K + c0;
  int lane = tid & 63, wave = tid >> 6;
  int l16 = lane & 15, quad = lane >> 4;
  int wm = (wave & 1) << 5, wn = (wave >> 1) << 5;
  f32x4 acc[2][2] = {};
  for (int k0 = 0; k0 < K; k0 += 64) {
    uint4 a00 = *(const uint4*)(a0p + k0), a01 = *(const uint4*)(a0p + k0 + 8);
    uint4 a10 = *(const uint4*)(a1p + k0), a11 = *(const uint4*)(a1p + k0 + 8);
    uint4 a20 = *(const uint4*)(a2p + k0), a21 = *(const uint4*)(a2p + k0 + 8);
    uint4 b00 = *(const uint4*)(b0p + k0), b01 = *(const uint4*)(b0p + k0 + 8);
    uint4 b10 = *(const uint4*)(b1p + k0), b11 = *(const uint4*)(b1p + k0 + 8);
    uint4 b20 = *(const uint4*)(b2p + k0), b21 = *(const uint4*)(b2p + k0 + 8);
    *(uint4*)&As0[dst0] = a00;  *(uint4*)&As0[dst1] = a01;
    *(uint4*)&As1[dst0] = a10;  *(uint4*)&As1[dst1] = a11;
    *(uint4*)&As2[dst0] = a20;  *(uint4*)&As2[dst1] = a21;
    *(uint4*)&Bs0[dst0] = b00;  *(uint4*)&Bs0[dst1] = b01;
    *(uint4*)&Bs1[dst0] = b10;  *(uint4*)&Bs1[dst1] = b11;
    *(uint4*)&Bs2[dst0] = b20;  *(uint4*)&Bs2[dst1] = b21;
    __syncthreads();
#pragma unroll
    for (int kk = 0; kk < 2; ++kk) {
      short8 af0[2], af1[2], af2[2], bf0[2], bf1[2], bf2[2];
#pragma unroll
      for (int mi = 0; mi < 2; ++mi) {
        int rr = wm + (mi << 4) + l16;
        int g = (kk << 2) + quad;
        int idx = rr * 64 + ((g ^ (rr & 7)) << 3);
        af0[mi] = *(const short8*)&As0[idx];
        af1[mi] = *(const short8*)&As1[idx];
        af2[mi] = *(const short8*)&As2[idx];
      }
#pragma unroll
      for (int nj = 0; nj < 2; ++nj) {
        int rr = wn + (nj << 4) + l16;
        int g = (kk << 2) + quad;
        int idx = rr * 64 + ((g ^ (rr & 7)) << 3);
        bf0[nj] = *(const short8*)&Bs0[idx];
        bf1[nj] = *(const short8*)&Bs1[idx];
        bf2[nj] = *(const short8*)&Bs2[idx];
      }
#pragma unroll
      for (int mi = 0; mi < 2; ++mi)
#pragma unroll
        for (int nj = 0; nj < 2; ++nj) {
          acc[mi][nj] = __builtin_amdgcn_mfma_f32_16x16x32_bf16(af2[mi], bf0[nj], acc[mi][nj], 0, 0, 0);
          acc[mi][nj] = __builtin_amdgcn_mfma_f32_16x16x32_bf16(af0[mi], bf2[nj], acc[mi][nj], 0, 0, 0);
          acc[mi][nj] = __builtin_amdgcn_mfma_f32_16x16x32_bf16(af1[mi], bf1[nj], acc[mi][nj], 0, 0, 0);
          acc[mi][nj] = __builtin_amdgcn_mfma_f32_16x16x32_bf16(af1[mi], bf0[nj], acc[mi][nj], 0, 0, 0);
          acc[mi][nj] = __builtin_amdgcn_mfma_f32_16x16x32_bf16(af0[mi], bf1[nj], acc[mi][nj], 0, 0, 0);
          acc[mi][nj] = __builtin_amdgcn_mfma_f32_16x16x32_bf16(af0[mi], bf0[nj], acc[mi][nj], 0, 0, 0);
        }
    }
    __syncthreads();
  }
#pragma unroll
  for (int mi = 0; mi < 2; ++mi)
#pragma unroll
    for (int nj = 0; nj < 2; ++nj)
#pragma unroll
      for (int r = 0; r < 4; ++r) {
        int mm = m0 + wm + (mi << 4) + (quad << 2) + r;
        int nn = n0 + wn + (nj << 4) + l16;
        C[(size_t)mm * N + nn] = acc[mi][nj][r];
      }
}

// ---------------- 64x64-tile bf16-A x bf16-B GEMM (final projection), fp32 out ----------------
__global__ __launch_bounds__(256) void gemm_b16A(const ushort* __restrict__ A,
                                                 const ushort* __restrict__ Bt,
                                                 float* __restrict__ C) {
  const int N = 2048, K = 2048;
  int m0 = blockIdx.y << 6, n0 = blockIdx.x << 6;
  __shared__ ushort As[64 * 64];
  __shared__ ushort Bs[64 * 64];
  int tid = threadIdx.x;
  int row = tid >> 2, c0 = (tid & 3) << 4;
  int sw = row & 7;
  int g0 = c0 >> 3;
  int dst0 = row * 64 + ((g0 ^ sw) << 3);
  int dst1 = row * 64 + (((g0 + 1) ^ sw) << 3);
  const ushort* aptr = A + (size_t)(m0 + row) * K + c0;
  const ushort* bptr = Bt + (size_t)(n0 + row) * K + c0;
  int lane = tid & 63, wave = tid >> 6;
  int l16 = lane & 15, quad = lane >> 4;
  int wm = (wave & 1) << 5, wn = (wave >> 1) << 5;
  f32x4 acc[2][2] = {};
  for (int k0 = 0; k0 < K; k0 += 64) {
    uint4 av0 = *(const uint4*)(aptr + k0);
    uint4 av1 = *(const uint4*)(aptr + k0 + 8);
    uint4 bv0 = *(const uint4*)(bptr + k0);
    uint4 bv1 = *(const uint4*)(bptr + k0 + 8);
    *(uint4*)&As[dst0] = av0;
    *(uint4*)&As[dst1] = av1;
    *(uint4*)&Bs[dst0] = bv0;
    *(uint4*)&Bs[dst1] = bv1;
    __syncthreads();
#pragma unroll
    for (int kk = 0; kk < 2; ++kk) {
      short8 af[2], bf[2];
#pragma unroll
      for (int mi = 0; mi < 2; ++mi) {
        int rr = wm + (mi << 4) + l16;
        int g = (kk << 2) + quad;
        af[mi] = *(const short8*)&As[rr * 64 + ((g ^ (rr & 7)) << 3)];
      }
#pragma unroll
      for (int nj = 0; nj < 2; ++nj) {
        int rr = wn + (nj << 4) + l16;
        int g = (kk << 2) + quad;
        bf[nj] = *(const short8*)&Bs[rr * 64 + ((g ^ (rr & 7)) << 3)];
      }
#pragma unroll
      for (int mi = 0; mi < 2; ++mi)
#pragma unroll
        for (int nj = 0; nj < 2; ++nj)
          acc[mi][nj] = __builtin_amdgcn_mfma_f32_16x16x32_bf16(af[mi], bf[nj], acc[mi][nj], 0, 0, 0);
    }
    __syncthreads();
  }
#pragma unroll
  for (int mi = 0; mi < 2; ++mi)
#pragma unroll
    for (int nj = 0; nj < 2; ++nj)
#pragma unroll
      for (int r = 0; r < 4; ++r) {
        int mm = m0 + wm + (mi << 4) + (quad << 2) + r;
        int nn = n0 + wn + (nj << 4) + l16;
        C[(size_t)mm * N + nn] = acc[mi][nj][r];
      }
}

// ---------------- clock pre-activation: x @ W_clock (2048x16), fp32 ----------------
__global__ __launch_bounds__(64) void wclock_k(const float* __restrict__ x,
                                               const float* __restrict__ Wc,
                                               float* __restrict__ out) {
  int m = blockIdx.x, lane = threadIdx.x;
  const float* xr = x + (size_t)m * Dd;
  float acc[16];
#pragma unroll
  for (int h = 0; h < 16; ++h) acc[h] = 0.f;
  for (int k = lane; k < Dd; k += 64) {
    float xv = xr[k];
    const float* wr = Wc + k * 16;
#pragma unroll
    for (int h = 0; h < 16; ++h) acc[h] += xv * wr[h];
  }
#pragma unroll
  for (int h = 0; h < 16; ++h) {
#pragma unroll
    for (int off = 32; off; off >>= 1) acc[h] += __shfl_down(acc[h], off);
  }
  if (lane == 0) {
    float* o = out + (size_t)m * 16;
#pragma unroll
    for (int h = 0; h < 16; ++h) o[h] = acc[h];
  }
}

// ---------------- per-chunk max of p = (x@W_p) + log(clock) over 256-t chunks ----------------
__global__ __launch_bounds__(128) void pmaxchunk_k(const float* __restrict__ Pf,
                                                   const float* __restrict__ cpre,
                                                   float* __restrict__ pmaxc) {
  int bh = blockIdx.x, ch = blockIdx.y, d = threadIdx.x;
  int b = bh >> 4, h = bh & 15;
  float mx = -1e30f;
  int t0 = ch << 8;
  for (int t = t0; t < t0 + 256; ++t) {
    float pr = Pf[((size_t)(b * Tt + t)) * Dd + h * 128 + d];
    float c = softplusf(cpre[(b * Tt + t) * Hh + h]) + 1e-6f;
    mx = fmaxf(mx, pr + logf(c));
  }
  pmaxc[(size_t)(bh * 8 + ch) * 128 + d] = mx;
}

// ======== blocked scan, stage 1: elementwise (rope, pe, gj, clock) + per-32t chunk sums ========
__global__ __launch_bounds__(128) void scan_ew_k(float* planes,
                                                 const float* __restrict__ cpre,
                                                 const float* __restrict__ pmaxc,
                                                 float* __restrict__ clockv,
                                                 float* __restrict__ sum_pe,
                                                 float* __restrict__ sum_gj,
                                                 float* __restrict__ sum_ck) {
  int ch = blockIdx.x, bh = blockIdx.y;
  int b = bh >> 4, h = bh & 15, d = threadIdx.x;
  float* Qf = planes;
  float* Kf = planes + (size_t)MD;
  float* Gf = planes + 2 * (size_t)MD;
  float* Pf = planes + 3 * (size_t)MD;
  float invf = (float)exp(-((double)((d & 63) * 2) / 128.0) * log(10000.0));
  float pmax = -1e30f;
#pragma unroll
  for (int c = 0; c < 8; ++c) pmax = fmaxf(pmax, pmaxc[(size_t)(bh * 8 + c) * 128 + d]);
  float s_pe = 0.f, s_gj = 0.f, s_ck = 0.f;
  int t0 = ch << 5;
#pragma unroll 4
  for (int i = 0; i < 32; ++i) {
    int t = t0 + i;
    size_t off = ((size_t)(b * Tt + t)) * Dd + h * 128 + d;
    float qv = Qf[off], kv = Kf[off], pv = Pf[off], gv = Gf[off];
    float clock = softplusf(cpre[(b * Tt + t) * Hh + h]) + 1e-6f;
    float ang = (float)t * invf;
    float c_ = cosf(ang), s_ = sinf(ang);
    float qp = __shfl_xor(qv, 1);
    float kp = __shfl_xor(kv, 1);
    float qrot = (d & 1) ? qp : -qp;
    float krot = (d & 1) ? kp : -kp;
    float qr = qv * c_ + qrot * s_;
    float kr = kv * c_ + krot * s_;
    float pe = expf(pv + logf(clock) - pmax);
    s_pe += pe;
    float gj = -softplusf(gv) * clock;
    s_gj += gj;
    Qf[off] = qr;
    Kf[off] = kr;
    Gf[off] = gj;     // gj for now; scan_apply_k turns it into e
    Pf[off] = pe;
    if (d == 0) {
      clockv[bh * Tt + t] = clock;
      s_ck += clock;
    }
  }
  size_t so = (size_t)(bh * 64 + ch) * 128 + d;
  sum_pe[so] = s_pe;
  sum_gj[so] = s_gj;
  if (d == 0) sum_ck[bh * 64 + ch] = s_ck;
}

// ======== blocked scan, stage 2: exclusive scan of chunk sums (pcs_cp falls out directly) ========
__global__ __launch_bounds__(128) void scan_off_k(const float* __restrict__ sum_pe,
                                                  const float* __restrict__ sum_gj,
                                                  const float* __restrict__ sum_ck,
                                                  float* __restrict__ pcs_cp,
                                                  float* __restrict__ goff,
                                                  float* __restrict__ coff) {
  int bh = blockIdx.x, d = threadIdx.x;
  float ppe = 0.f, pgj = 0.f, pck = 0.f;
  for (int c = 0; c < 64; ++c) {
    size_t o = (size_t)(bh * 64 + c) * 128 + d;
    pcs_cp[o] = ppe;
    goff[o] = pgj;
    ppe += sum_pe[o];
    pgj += sum_gj[o];
    if (d == 0) { coff[bh * 64 + c] = pck; pck += sum_ck[bh * 64 + c]; }
  }
}

// ======== blocked scan, stage 3: within-chunk gcs -> e (Gf), and ccsv ========
__global__ __launch_bounds__(128) void scan_apply_k(float* planes,
                                                    const float* __restrict__ goff,
                                                    const float* __restrict__ coff,
                                                    const float* __restrict__ clockv,
                                                    float* __restrict__ ccsv) {
  int ch = blockIdx.x, bh = blockIdx.y;
  int b = bh >> 4, h = bh & 15, d = threadIdx.x;
  float* Gf = planes + 2 * (size_t)MD;
  float g = goff[(size_t)(bh * 64 + ch) * 128 + d];
  float ccs = (d == 0) ? coff[bh * 64 + ch] : 0.f;
  int t0 = ch << 5;
#pragma unroll 4
  for (int i = 0; i < 32; ++i) {
    int t = t0 + i;
    size_t off = ((size_t)(b * Tt + t)) * Dd + h * 128 + d;
    float gj = Gf[off];
    g += gj;
    float e = expf(fminf(fmaxf(g, -50.f), 40.f));
    Gf[off] = e;
    if (d == 0) {
      ccs += clockv[bh * Tt + t];
      ccsv[bh * Tt + t] = ccs;
    }
  }
}

// ---------------- MFMA flash attention: 128 q-rows/block, 8 waves x 16 rows ----------------
// QK^T via 2-term split-bf16 MFMA; PV via MFMA with hi/lo split P and tr-read V fragments.
// K re-staged 16x (vs 32x at 64-row blocks); 16 waves/CU occupancy.
__global__ __launch_bounds__(512, 2) void attn_mfma_k(const float* __restrict__ planes,
                                                      const ushort* __restrict__ Vb,
                                                      const float* __restrict__ clockv,
                                                      const float* __restrict__ ccsv,
                                                      const float* __restrict__ pcs_cp,
                                                      ushort* __restrict__ attnout) {
  __shared__ float smemf[18432];            // 72 KB -> 2 blocks/CU, 16 waves/CU
  ushort* Khi = (ushort*)smemf;             // [32 keys][384 dims] swizzled  @0      (24576 B)
  ushort* Klo = Khi + 12288;                //                              @24576  (24576 B)
  ushort* Vsm = Khi + 24576;                // [32 keys][128 dims] 4x16-subtiled @49152 (8192 B)
  unsigned* Pu = (unsigned*)(smemf + 14336);// 8 waves x [16 rows][32 keys] u32 @57344 (16384 B)
  float* pcsL = smemf;                      // phase alias @0: [64][128] f32 (32 KB)
  ushort* qscr = (ushort*)(smemf + 8192);   // phase alias @32768: 4 x 8 KB

  int tid = threadIdx.x;
  int lane = tid & 63, wave = tid >> 6;     // wave 0..7
  int l15 = lane & 15, qd = lane >> 4;
  int qt0 = blockIdx.x << 7;                // 128 q rows per block
  int bh = blockIdx.y, b = bh >> 4, h = bh & 15;
  const float* Qf = planes;
  const float* Kf = planes + (size_t)MD;
  const float* Ef = planes + 2 * (size_t)MD;
  const float* Pe = planes + 3 * (size_t)MD;
  size_t pbase = ((size_t)b * Tt) * Dd + h * 128;

  // ---- Q prep in 2 rounds: rows 0..63 (waves 0..3), rows 64..127 (waves 4..7) ----
  short8 qh[12], ql[12];
  int wl = wave & 3;
  int rloc = lane >> 2;                     // 0..15, row within wave tile
  {
    ushort* sh = qscr + (wl << 12);         // [16][128] hi ushort (4 KB)
    ushort* sl = sh + 2048;                 // lo (4 KB)
#pragma unroll
    for (int rd = 0; rd < 2; ++rd) {
      // phase A: pcs replay for this round's 64 rows (256 threads; chunk==32 rows)
      if (tid < 256) {
        int d = tid & 127, seg = tid >> 7;
        int rbase = (rd << 6) + (seg << 5);
        float pcs = pcs_cp[((size_t)bh * 64 + (qt0 >> 5) + (rd << 1) + seg) * 128 + d];
        for (int i = 0; i < 32; ++i) {
          pcs += Pe[pbase + (size_t)(qt0 + rbase + i) * Dd + d];
          pcsL[((seg << 5) + i) * 128 + d] = pcs;
        }
      }
      __syncthreads();
      int part = ((wave >> 2) == rd);
      int grow = qt0 + (rd << 6) + (wl << 4) + rloc;
      float ccsr = __builtin_amdgcn_rcpf(ccsv[bh * Tt + grow]);
      size_t goffq = pbase + (size_t)grow * Dd;
#pragma unroll
      for (int cd = 0; cd < 3; ++cd) {
        __syncthreads();
        if (part) {
#pragma unroll
          for (int j = 0; j < 4; ++j) {
            int d0 = ((lane & 3) << 5) + (j << 3);   // 8 dims
            float qv[8], mv[8];
            *(float4*)&qv[0] = *(const float4*)(Qf + goffq + d0);
            *(float4*)&qv[4] = *(const float4*)(Qf + goffq + d0 + 4);
            if (cd == 0) {
              *(float4*)&mv[0] = *(const float4*)&pcsL[((wl << 4) + rloc) * 128 + d0];
              *(float4*)&mv[4] = *(const float4*)&pcsL[((wl << 4) + rloc) * 128 + d0 + 4];
#pragma unroll
              for (int i = 0; i < 8; ++i) qv[i] = qv[i] * __builtin_amdgcn_rcpf(mv[i] + 1e-8f);
            } else if (cd == 1) {
              *(float4*)&mv[0] = *(const float4*)(Ef + goffq + d0);
              *(float4*)&mv[4] = *(const float4*)(Ef + goffq + d0 + 4);
#pragma unroll
              for (int i = 0; i < 8; ++i) qv[i] = qv[i] * mv[i];
            } else {
#pragma unroll
              for (int i = 0; i < 8; ++i) qv[i] = qv[i] * ccsr;
            }
            ushort hi8[8], lo8[8];
#pragma unroll
            for (int i = 0; i < 8; ++i) {
              ushort a = f2b(qv[i]); hi8[i] = a; lo8[i] = f2b(qv[i] - b2f(a));
            }
            int g = ((lane & 3) << 2) + j;          // dim group 0..15
            int phys = (g & 8) | ((g ^ rloc) & 7);
            *(uint4*)&sh[rloc * 128 + (phys << 3)] = *(uint4*)hi8;
            *(uint4*)&sl[rloc * 128 + (phys << 3)] = *(uint4*)lo8;
          }
        }
        __syncthreads();
        if (part) {
#pragma unroll
          for (int ksl = 0; ksl < 4; ++ksl) {
            int g = (ksl << 2) + qd;
            int phys = (g & 8) | ((g ^ l15) & 7);
            qh[(cd << 2) + ksl] = *(const short8*)&sh[l15 * 128 + (phys << 3)];
            ql[(cd << 2) + ksl] = *(const short8*)&sl[l15 * 128 + (phys << 3)];
          }
        }
      }
      __syncthreads();                      // pcsL/qscr reuse (and Khi alias) safe
    }
  }

  // ---- main loop over 64 key-tiles of 32 ----
  float mi4[4], li4[4];
  f32x4 acc_pv[8] = {};
#pragma unroll
  for (int r = 0; r < 4; ++r) { mi4[r] = -1e30f; li4[r] = 0.f; }
  const float scl = 0.05103103630798287f;   // 1/sqrt(384)
  const ushort* vbase = Vb + pbase;
  unsigned* PuW = Pu + (wave << 9);         // per-wave 2 KB
  unsigned VsmA = (unsigned)(size_t)Vsm;    // LDS byte address (low 32 bits of flat)
  int kk = tid >> 4;                        // key 0..31 (staging role)
  int kdb = tid & 15;                       // 8-dim block (staging role)

  for (int st = 0; st < 64; ++st) {
    int s0 = st << 5;
    __syncthreads();                        // all reads of K/V tile (st-1) done
    // ---- stage K (3 cat slots, RTZ-hi + exact-residual-lo split) + V tile (4x16 subtiles) ----
    {
      size_t roff = pbase + (size_t)(s0 + kk) * Dd + (kdb << 3);
      float ck = clockv[bh * Tt + s0 + kk];
      float kv[8], pev[8], ev[8];
      *(float4*)&kv[0] = *(const float4*)(Kf + roff);
      *(float4*)&kv[4] = *(const float4*)(Kf + roff + 4);
      *(float4*)&pev[0] = *(const float4*)(Pe + roff);
      *(float4*)&pev[4] = *(const float4*)(Pe + roff + 4);
      *(float4*)&ev[0] = *(const float4*)(Ef + roff);
      *(float4*)&ev[4] = *(const float4*)(Ef + roff + 4);
#pragma unroll
      for (int slot = 0; slot < 3; ++slot) {
        float val[8];
        if (slot == 0) {
#pragma unroll
          for (int i = 0; i < 8; ++i) val[i] = kv[i] * pev[i];
        } else if (slot == 1) {
#pragma unroll
          for (int i = 0; i < 8; ++i) val[i] = kv[i] * __builtin_amdgcn_rcpf(ev[i] + 1e-8f);
        } else {
#pragma unroll
          for (int i = 0; i < 8; ++i) val[i] = kv[i] * ck;
        }
        unsigned ub[8], ul[8];
#pragma unroll
        for (int i = 0; i < 8; ++i) {
          union { float f; unsigned u; } c; c.f = val[i];
          ub[i] = c.u;
          union { unsigned u; float f; } hm; hm.u = c.u & 0xffff0000u;
          union { float f; unsigned u; } lr; lr.f = val[i] - hm.f;
          ul[i] = lr.u;
        }
        uint4 hi4, lo4;
        hi4.x = (ub[0] >> 16) | (ub[1] & 0xffff0000u);
        hi4.y = (ub[2] >> 16) | (ub[3] & 0xffff0000u);
        hi4.z = (ub[4] >> 16) | (ub[5] & 0xffff0000u);
        hi4.w = (ub[6] >> 16) | (ub[7] & 0xffff0000u);
        lo4.x = (ul[0] >> 16) | (ul[1] & 0xffff0000u);
        lo4.y = (ul[2] >> 16) | (ul[3] & 0xffff0000u);
        lo4.z = (ul[4] >> 16) | (ul[5] & 0xffff0000u);
        lo4.w = (ul[6] >> 16) | (ul[7] & 0xffff0000u);
        int g = (slot << 4) + kdb;
        int phys = (g & ~7) | ((g ^ kk) & 7);
        *(uint4*)&Khi[kk * 384 + (phys << 3)] = hi4;
        *(uint4*)&Klo[kk * 384 + (phys << 3)] = lo4;
      }
      // V: subtile layout: byte = chunk*1024 + (m&1)*512 + (m>>1)*128 + (key&3)*32 + half*16
      const ushort* vsrc = vbase + (size_t)(s0 + kk) * Dd + (kdb << 3);
      int vbyte = ((kdb >> 1) << 10) + (((kk >> 2) & 1) << 9) + ((kk >> 3) << 7) +
                  ((kk & 3) << 5) + ((kdb & 1) << 4);
      *(uint4*)((char*)Vsm + vbyte) = *(const uint4*)vsrc;
    }
    __syncthreads();
    // ---- QK^T: 2-term split-bf16 MFMA (3 terms, smallest first) ----
    f32x4 acc0 = {}, acc1 = {};
#pragma unroll
    for (int ks = 0; ks < 12; ++ks) {
      int g = (ks << 2) + qd;
      int p0i = (g & ~7) | ((g ^ l15) & 7);
      int p1i = (g & ~7) | ((g ^ (16 + l15)) & 7);
      short8 b0h = *(const short8*)&Khi[l15 * 384 + (p0i << 3)];
      short8 b0l = *(const short8*)&Klo[l15 * 384 + (p0i << 3)];
      short8 b1h = *(const short8*)&Khi[(16 + l15) * 384 + (p1i << 3)];
      short8 b1l = *(const short8*)&Klo[(16 + l15) * 384 + (p1i << 3)];
      acc0 = __builtin_amdgcn_mfma_f32_16x16x32_bf16(ql[ks], b0h, acc0, 0, 0, 0);
      acc0 = __builtin_amdgcn_mfma_f32_16x16x32_bf16(qh[ks], b0l, acc0, 0, 0, 0);
      acc0 = __builtin_amdgcn_mfma_f32_16x16x32_bf16(qh[ks], b0h, acc0, 0, 0, 0);
      acc1 = __builtin_amdgcn_mfma_f32_16x16x32_bf16(ql[ks], b1h, acc1, 0, 0, 0);
      acc1 = __builtin_amdgcn_mfma_f32_16x16x32_bf16(qh[ks], b1l, acc1, 0, 0, 0);
      acc1 = __builtin_amdgcn_mfma_f32_16x16x32_bf16(qh[ks], b1h, acc1, 0, 0, 0);
    }
    // ---- online softmax (rows = qd*4+r, cols = keys via l15); P -> Pu (hi/lo packed) ----
#pragma unroll
    for (int r = 0; r < 4; ++r) {
      float sa = acc0[r] * scl, sb = acc1[r] * scl;
      float mx = fmaxf(sa, sb);
#pragma unroll
      for (int m = 1; m < 16; m <<= 1) mx = fmaxf(mx, __shfl_xor(mx, m));
      float mn = fmaxf(mi4[r], mx);
      float al = expf(mi4[r] - mn);
      float p0 = expf(sa - mn), p1 = expf(sb - mn);
      float rs = p0 + p1;
#pragma unroll
      for (int m = 1; m < 16; m <<= 1) rs += __shfl_xor(rs, m);
      li4[r] = li4[r] * al + rs;
      mi4[r] = mn;
#pragma unroll
      for (int n0 = 0; n0 < 8; ++n0) acc_pv[n0][r] *= al;
      int R = (qd << 2) + r;
      {
        union { float f; unsigned u; } c0, c1; c0.f = p0; c1.f = p1;
        union { unsigned u; float f; } m0_, m1_;
        m0_.u = c0.u & 0xffff0000u; m1_.u = c1.u & 0xffff0000u;
        union { float f; unsigned u; } d0_, d1_;
        d0_.f = p0 - m0_.f; d1_.f = p1 - m1_.f;
        unsigned u0 = (c0.u >> 16) | (d0_.u & 0xffff0000u);
        unsigned u1 = (c1.u >> 16) | (d1_.u & 0xffff0000u);
        int r7 = R & 7;
        char* pb = (char*)PuW + (R << 7) + ((l15 & 3) << 2);
        *(unsigned*)(pb + (((l15 >> 2) ^ r7) << 4)) = u0;
        *(unsigned*)(pb + ((((l15 >> 2) + 4) ^ r7) << 4)) = u1;
      }
    }
    // ---- PV via MFMA: A = P hi/lo fragments (wave-private Pu), B = V tr-read fragments ----
    {
      unsigned pw[8];
      {
        const char* pb = (const char*)PuW + l15 * 128;
        uint4 w0 = *(const uint4*)(pb + ((((qd << 1)) ^ (l15 & 7)) << 4));
        uint4 w1 = *(const uint4*)(pb + ((((qd << 1) | 1) ^ (l15 & 7)) << 4));
        pw[0] = w0.x; pw[1] = w0.y; pw[2] = w0.z; pw[3] = w0.w;
        pw[4] = w1.x; pw[5] = w1.y; pw[6] = w1.z; pw[7] = w1.w;
      }
      union { unsigned u[4]; short8 s; } uph, upl;
#pragma unroll
      for (int i = 0; i < 4; ++i) {
        uph.u[i] = (pw[2 * i] & 0xffffu) | (pw[2 * i + 1] << 16);
        upl.u[i] = (pw[2 * i] >> 16) | (pw[2 * i + 1] & 0xffff0000u);
      }
      short4v tv[16];
#pragma unroll
      for (int n0 = 0; n0 < 8; ++n0) {
        unsigned a0 = VsmA + (n0 << 10) + (lane << 3);
        tv[2 * n0] = tr16(a0);              // keys qd*8 .. +3 at dim col l15
        tv[2 * n0 + 1] = tr16(a0 + 512);    // keys qd*8+4 .. +7
      }
      asm volatile("s_waitcnt lgkmcnt(0)" ::: "memory");
      __builtin_amdgcn_sched_barrier(0);
#pragma unroll
      for (int n0 = 0; n0 < 8; ++n0) {
        short8 bv = __builtin_shufflevector(tv[2 * n0], tv[2 * n0 + 1], 0, 1, 2, 3, 4, 5, 6, 7);
        acc_pv[n0] = __builtin_amdgcn_mfma_f32_16x16x32_bf16(uph.s, bv, acc_pv[n0], 0, 0, 0);
        acc_pv[n0] = __builtin_amdgcn_mfma_f32_16x16x32_bf16(upl.s, bv, acc_pv[n0], 0, 0, 0);
      }
    }
  }
  // ---- epilogue: normalize, bf16 out (row = qd*4+r, dim = n0*16+l15) ----
#pragma unroll
  for (int r = 0; r < 4; ++r) {
    float inv = 1.f / li4[r];
    int trow = qt0 + (wave << 4) + (qd << 2) + r;
    ushort* orow = attnout + ((size_t)(b * Tt + trow)) * Dd + h * 128 + l15;
#pragma unroll
    for (int n0 = 0; n0 < 8; ++n0)
      orow[n0 << 4] = f2b(acc_pv[n0][r] * inv);
  }
}

extern "C" void kernel_launch(void* const* d_in, const int* in_sizes, int n_in,
                              void* d_out, int out_size, void* d_ws, size_t ws_size,
                              hipStream_t stream) {
  const float* x = (const float*)d_in[0];
  const float* Wq = (const float*)d_in[1];
  const float* Wk = (const float*)d_in[2];
  const float* Wv = (const float*)d_in[3];
  const float* Wg = (const float*)d_in[4];
  const float* Wp = (const float*)d_in[5];
  const float* Wclk = (const float*)d_in[6];
  const float* Wc = (const float*)d_in[7];

  // ---- workspace layout (~178 MiB) ----
  float* planes = (float*)d_ws;                       // 4 * MD fp32: qr | kr | e | pe
  float* Aq = planes;
  float* Bk = planes + (size_t)MD;
  float* Ce = planes + 2 * (size_t)MD;
  float* Dp = planes + 3 * (size_t)MD;
  ushort* Vb = (ushort*)(planes + 4 * (size_t)MD);    // MD bf16
  float* cpre = (float*)(Vb + (size_t)MD);            // 65536
  float* clockv = cpre + 65536;                       // 65536
  float* ccsv = clockv + 65536;                       // 65536
  float* pmaxc = ccsv + 65536;                        // 32768
  float* pcs_cp = pmaxc + 32768;                      // 32*64*128 = 262144
  ushort* Wt0 = (ushort*)(pcs_cp + 262144);           // 3 x Dd*Dd bf16 (projection phase)
  ushort* Wt1 = Wt0 + (size_t)Dd * Dd;
  ushort* Wt2 = Wt1 + (size_t)Dd * Dd;
  ushort* attnout = Wt0;                              // reuse Wt region (dead after projections)
  ushort* WcT0 = (ushort*)Ce;                         // post-attention: reuse e-plane for Wc^T
  // x-split planes (48 MB) live in Dp (32 MB) + Vb (16 MB) — dead until P/V projections,
  // which read x directly and run after all x-split consumers (stream-ordered).
  ushort* xs0 = (ushort*)Dp;                          // MD bf16
  ushort* xs1 = xs0 + (size_t)MD;                     // MD bf16
  ushort* xs2 = (ushort*)Vb;                          // MD bf16
  // scan temporaries live in the Wt2 region (dead during the scan phase; 3.2 MB << 8.4 MB)
  float* sum_pe = (float*)Wt2;                        // 262144
  float* sum_gj = sum_pe + 262144;                    // 262144
  float* goff_  = sum_gj + 262144;                    // 262144
  float* sum_ck = goff_ + 262144;                     // 2048
  float* coff_  = sum_ck + 2048;                      // 2048

  size_t needed = (size_t)((char*)(Wt2 + (size_t)Dd * Dd) - (char*)d_ws);
  if (ws_size < needed) return;  // diagnostic: absmax ~= 4.69 => ws too small

  dim3 tg(Dd / 64, Dd / 64), gg(Dd / 64, Mm / 64);

  // x split planes (once) — removes per-block re-splitting of A in Q/K/G projections
  xsplit_k<<<dim3(MD / 8 / 256), 256, 0, stream>>>(x, xs0, xs1, xs2);

  // Q, K projections: 3-term (pre-split A, 2 planes each side) — error ~2^-17, same class
  // as the attention QK split; safe because scores only feed softmax.
  split_transposeN<2><<<tg, 256, 0, stream>>>(Wq, Wt0, Wt1, nullptr);
  gemm_pre3<<<gg, 256, 0, stream>>>(xs0, xs1, Wt0, Wt1, Aq);
  split_transposeN<2><<<tg, 256, 0, stream>>>(Wk, Wt0, Wt1, nullptr);
  gemm_pre3<<<gg, 256, 0, stream>>>(xs0, xs1, Wt0, Wt1, Bk);
  // G projection: keep 6-term — gj errors amplify through the 2048-long cumsum exponent.
  split_transposeN<3><<<tg, 256, 0, stream>>>(Wg, Wt0, Wt1, Wt2);
  gemm_pre<<<gg, 256, 0, stream>>>(xs0, xs1, xs2, Wt0, Wt1, Wt2, Ce);
  // P, V projections: 3-term direct-x path (outputs overwrite the now-dead xs planes).
  // P only feeds exp(p - pmax); V is rounded to bf16 on output anyway.
  split_transposeN<2><<<tg, 256, 0, stream>>>(Wp, Wt0, Wt1, nullptr);
  gemm63<0><<<gg, 256, 0, stream>>>(x, Wt0, Wt1, (void*)Dp);
  split_transposeN<2><<<tg, 256, 0, stream>>>(Wv, Wt0, Wt1, nullptr);
  gemm63<1><<<gg, 256, 0, stream>>>(x, Wt0, Wt1, (void*)Vb);

  // clock pre-activation, chunked p_max
  wclock_k<<<dim3(Mm), dim3(64), 0, stream>>>(x, Wclk, cpre);
  pmaxchunk_k<<<dim3(Bb * Hh, 8), dim3(128), 0, stream>>>(Dp, cpre, pmaxc);

  // blocked scan: elementwise+partials, chunk-offset scan, apply
  scan_ew_k<<<dim3(64, Bb * Hh), dim3(128), 0, stream>>>(planes, cpre, pmaxc, clockv,
                                                         sum_pe, sum_gj, sum_ck);
  scan_off_k<<<dim3(Bb * Hh), dim3(128), 0, stream>>>(sum_pe, sum_gj, sum_ck,
                                                      pcs_cp, goff_, coff_);
  scan_apply_k<<<dim3(64, Bb * Hh), dim3(128), 0, stream>>>(planes, goff_, coff_, clockv, ccsv);

  // MFMA flash attention -> attnout (bf16, in dead Wt region)
  attn_mfma_k<<<dim3(Tt / 128, Bb * Hh), dim3(512), 0, stream>>>(planes, Vb, clockv, ccsv, pcs_cp, attnout);

  // Wc^T (1 plane, into dead e-plane), then final GEMM -> fp32 d_out
  split_transposeN<1><<<tg, 256, 0, stream>>>(Wc, WcT0, nullptr, nullptr);
  gemm_b16A<<<gg, 256, 0, stream>>>(attnout, WcT0, (float*)d_out);
}

// Round 7
// 1712.427 us; speedup vs baseline: 1.3533x; 1.0964x over previous
//
#include <hip/hip_runtime.h>

typedef unsigned short ushort;
typedef __attribute__((ext_vector_type(8))) short short8;
typedef __attribute__((ext_vector_type(4))) short short4v;
typedef __attribute__((ext_vector_type(4))) float f32x4;

#define Bb 2
#define Tt 2048
#define Dd 2048
#define Hh 16
#define Mm 4096                 // B*T
#define MD 8388608u             // Mm*Dd

__device__ __forceinline__ float b2f(ushort u) {
  union { unsigned int ui; float f; } v; v.ui = ((unsigned int)u) << 16; return v.f;
}
__device__ __forceinline__ ushort f2b(float f) {
  union { float f; unsigned int u; } v; v.f = f;
  unsigned int r = (v.u + 0x7fffu + ((v.u >> 16) & 1u)) >> 16;
  return (ushort)r;
}
__device__ __forceinline__ void split3(float v, ushort& s0, ushort& s1, ushort& s2) {
  ushort a = f2b(v);        float f0 = b2f(a);
  float r1 = v - f0;        ushort b = f2b(r1);  float f1 = b2f(b);
  float r2 = r1 - f1;       ushort c = f2b(r2);
  s0 = a; s1 = b; s2 = c;
}
// RTZ hi + exact residual chain
__device__ __forceinline__ void split3_rtz(float v, ushort& s0, ushort& s1, ushort& s2) {
  union { float f; unsigned u; } c; c.f = v;
  s0 = (ushort)(c.u >> 16);
  union { unsigned u; float f; } h; h.u = c.u & 0xffff0000u;
  float r1 = v - h.f;
  union { float f; unsigned u; } c1; c1.f = r1;
  s1 = (ushort)(c1.u >> 16);
  union { unsigned u; float f; } h1; h1.u = c1.u & 0xffff0000u;
  float r2 = r1 - h1.f;
  s2 = f2b(r2);
}
// 2-term split: RTZ hi + RNE residual (rep error ~2^-17 rel)
__device__ __forceinline__ void split2(float v, ushort& s0, ushort& s1) {
  union { float f; unsigned u; } c; c.f = v;
  s0 = (ushort)(c.u >> 16);
  union { unsigned u; float f; } h; h.u = c.u & 0xffff0000u;
  s1 = f2b(v - h.f);
}
__device__ __forceinline__ float softplusf(float x) {
  return fmaxf(x, 0.f) + log1pf(expf(-fabsf(x)));
}
__device__ __forceinline__ short4v tr16(unsigned a) {
  short4v d;
  asm volatile("ds_read_b64_tr_b16 %0, %1" : "=v"(d) : "v"(a));
  return d;
}

// ---------------- x -> 3 bf16 split planes (row-major, no transpose) ----------------
__global__ __launch_bounds__(256) void xsplit_k(const float* __restrict__ x,
                                                ushort* __restrict__ S0,
                                                ushort* __restrict__ S1,
                                                ushort* __restrict__ S2) {
  size_t i = ((size_t)blockIdx.x * 256 + threadIdx.x) * 8;
  float v[8];
  *(float4*)&v[0] = *(const float4*)(x + i);
  *(float4*)&v[4] = *(const float4*)(x + i + 4);
  ushort h0[8], h1[8], h2[8];
#pragma unroll
  for (int j = 0; j < 8; ++j) split3_rtz(v[j], h0[j], h1[j], h2[j]);
  *(uint4*)(S0 + i) = *(uint4*)h0;
  *(uint4*)(S1 + i) = *(uint4*)h1;
  *(uint4*)(S2 + i) = *(uint4*)h2;
}

// -------- transpose one DxD fp32 matrix -> NP bf16 split planes, transposed (NP=1,2,3) --------
template <int NP>
__global__ __launch_bounds__(256) void split_transposeN(const float* __restrict__ W,
                                                        ushort* __restrict__ T0,
                                                        ushort* __restrict__ T1,
                                                        ushort* __restrict__ T2) {
  __shared__ float tile[64][68];
  int k0 = blockIdx.x << 6, n0 = blockIdx.y << 6;
  int r = threadIdx.x >> 2, c0 = (threadIdx.x & 3) << 4;
  const float* src = W + (size_t)(k0 + r) * Dd + n0 + c0;
#pragma unroll
  for (int q = 0; q < 4; ++q)
    *(float4*)&tile[r][c0 + 4 * q] = *(const float4*)(src + 4 * q);
  __syncthreads();
  ushort h0[16], h1[16], h2[16];
#pragma unroll
  for (int i = 0; i < 16; ++i) {
    float v = tile[c0 + i][r];
    if (NP == 1) {
      h0[i] = f2b(v);
    } else if (NP == 2) {
      ushort a = f2b(v); h0[i] = a; h1[i] = f2b(v - b2f(a));
    } else {
      split3(v, h0[i], h1[i], h2[i]);
    }
  }
  size_t o = (size_t)(n0 + r) * Dd + k0 + c0;
  *(uint4*)(T0 + o) = *(uint4*)&h0[0];  *(uint4*)(T0 + o + 8) = *(uint4*)&h0[8];
  if (NP >= 2) { *(uint4*)(T1 + o) = *(uint4*)&h1[0];  *(uint4*)(T1 + o + 8) = *(uint4*)&h1[8]; }
  if (NP >= 3) { *(uint4*)(T2 + o) = *(uint4*)&h2[0];  *(uint4*)(T2 + o + 8) = *(uint4*)&h2[8]; }
}

// ======== 128x128-tile 3-term GEMM, PRE-SPLIT A (2+2 bf16 planes): Q, K ========
__global__ __launch_bounds__(512) void gemm128_pre2(const ushort* __restrict__ A0,
                                                    const ushort* __restrict__ A1,
                                                    const ushort* __restrict__ B0,
                                                    const ushort* __restrict__ B1,
                                                    float* __restrict__ C) {
  const int N = 2048, K = 2048;
  int m0 = blockIdx.y << 7, n0 = blockIdx.x << 7;
  __shared__ ushort As0[8192], As1[8192], Bs0[8192], Bs1[8192];
  int tid = threadIdx.x;
  int row = tid >> 2, c0 = (tid & 3) << 4;
  int sw = row & 7, g0 = c0 >> 3;
  int dst0 = row * 64 + ((g0 ^ sw) << 3);
  int dst1 = row * 64 + (((g0 + 1) ^ sw) << 3);
  const ushort* a0p = A0 + (size_t)(m0 + row) * K + c0;
  const ushort* a1p = A1 + (size_t)(m0 + row) * K + c0;
  const ushort* b0p = B0 + (size_t)(n0 + row) * K + c0;
  const ushort* b1p = B1 + (size_t)(n0 + row) * K + c0;
  int lane = tid & 63, wave = tid >> 6;
  int l16 = lane & 15, quad = lane >> 4;
  int wm = (wave & 1) << 6, wn = (wave >> 1) << 5;
  f32x4 acc[4][2] = {};
  for (int k0 = 0; k0 < K; k0 += 64) {
    uint4 a00 = *(const uint4*)(a0p + k0), a01 = *(const uint4*)(a0p + k0 + 8);
    uint4 a10 = *(const uint4*)(a1p + k0), a11 = *(const uint4*)(a1p + k0 + 8);
    uint4 b00 = *(const uint4*)(b0p + k0), b01 = *(const uint4*)(b0p + k0 + 8);
    uint4 b10 = *(const uint4*)(b1p + k0), b11 = *(const uint4*)(b1p + k0 + 8);
    *(uint4*)&As0[dst0] = a00;  *(uint4*)&As0[dst1] = a01;
    *(uint4*)&As1[dst0] = a10;  *(uint4*)&As1[dst1] = a11;
    *(uint4*)&Bs0[dst0] = b00;  *(uint4*)&Bs0[dst1] = b01;
    *(uint4*)&Bs1[dst0] = b10;  *(uint4*)&Bs1[dst1] = b11;
    __syncthreads();
#pragma unroll
    for (int kk = 0; kk < 2; ++kk) {
      short8 af0[4], af1[4], bf0[2], bf1[2];
#pragma unroll
      for (int mi = 0; mi < 4; ++mi) {
        int rr = wm + (mi << 4) + l16;
        int g = (kk << 2) + quad;
        int idx = rr * 64 + ((g ^ (rr & 7)) << 3);
        af0[mi] = *(const short8*)&As0[idx];
        af1[mi] = *(const short8*)&As1[idx];
      }
#pragma unroll
      for (int nj = 0; nj < 2; ++nj) {
        int rr = wn + (nj << 4) + l16;
        int g = (kk << 2) + quad;
        int idx = rr * 64 + ((g ^ (rr & 7)) << 3);
        bf0[nj] = *(const short8*)&Bs0[idx];
        bf1[nj] = *(const short8*)&Bs1[idx];
      }
#pragma unroll
      for (int mi = 0; mi < 4; ++mi)
#pragma unroll
        for (int nj = 0; nj < 2; ++nj) {
          acc[mi][nj] = __builtin_amdgcn_mfma_f32_16x16x32_bf16(af1[mi], bf0[nj], acc[mi][nj], 0, 0, 0);
          acc[mi][nj] = __builtin_amdgcn_mfma_f32_16x16x32_bf16(af0[mi], bf1[nj], acc[mi][nj], 0, 0, 0);
          acc[mi][nj] = __builtin_amdgcn_mfma_f32_16x16x32_bf16(af0[mi], bf0[nj], acc[mi][nj], 0, 0, 0);
        }
    }
    __syncthreads();
  }
#pragma unroll
  for (int mi = 0; mi < 4; ++mi)
#pragma unroll
    for (int nj = 0; nj < 2; ++nj)
#pragma unroll
      for (int r = 0; r < 4; ++r) {
        int mm = m0 + wm + (mi << 4) + (quad << 2) + r;
        int nn = n0 + wn + (nj << 4) + l16;
        C[(size_t)mm * N + nn] = acc[mi][nj][r];
      }
}

// ======== 128x128-tile 3-term GEMM, fp32 A split in-kernel (2 B planes): P, V ========
template <int BF16OUT>
__global__ __launch_bounds__(512) void gemm128_split2(const float* __restrict__ A,
                                                      const ushort* __restrict__ B0,
                                                      const ushort* __restrict__ B1,
                                                      void* __restrict__ CBase) {
  const int N = 2048, K = 2048;
  int m0 = blockIdx.y << 7, n0 = blockIdx.x << 7;
  __shared__ ushort As0[8192], As1[8192], Bs0[8192], Bs1[8192];
  int tid = threadIdx.x;
  int row = tid >> 2, c0 = (tid & 3) << 4;
  int sw = row & 7, g0 = c0 >> 3;
  int dst0 = row * 64 + ((g0 ^ sw) << 3);
  int dst1 = row * 64 + (((g0 + 1) ^ sw) << 3);
  const float* aptr = A + (size_t)(m0 + row) * K + c0;
  const ushort* b0p = B0 + (size_t)(n0 + row) * K + c0;
  const ushort* b1p = B1 + (size_t)(n0 + row) * K + c0;
  int lane = tid & 63, wave = tid >> 6;
  int l16 = lane & 15, quad = lane >> 4;
  int wm = (wave & 1) << 6, wn = (wave >> 1) << 5;
  f32x4 acc[4][2] = {};
  for (int k0 = 0; k0 < K; k0 += 64) {
    float av[16];
#pragma unroll
    for (int q = 0; q < 4; ++q)
      *(float4*)&av[4 * q] = *(const float4*)(aptr + k0 + 4 * q);
    ushort a0[16], a1[16];
#pragma unroll
    for (int i = 0; i < 16; ++i) split2(av[i], a0[i], a1[i]);
    uint4 b00 = *(const uint4*)(b0p + k0), b01 = *(const uint4*)(b0p + k0 + 8);
    uint4 b10 = *(const uint4*)(b1p + k0), b11 = *(const uint4*)(b1p + k0 + 8);
    *(uint4*)&As0[dst0] = *(uint4*)&a0[0];  *(uint4*)&As0[dst1] = *(uint4*)&a0[8];
    *(uint4*)&As1[dst0] = *(uint4*)&a1[0];  *(uint4*)&As1[dst1] = *(uint4*)&a1[8];
    *(uint4*)&Bs0[dst0] = b00;  *(uint4*)&Bs0[dst1] = b01;
    *(uint4*)&Bs1[dst0] = b10;  *(uint4*)&Bs1[dst1] = b11;
    __syncthreads();
#pragma unroll
    for (int kk = 0; kk < 2; ++kk) {
      short8 af0[4], af1[4], bf0[2], bf1[2];
#pragma unroll
      for (int mi = 0; mi < 4; ++mi) {
        int rr = wm + (mi << 4) + l16;
        int g = (kk << 2) + quad;
        int idx = rr * 64 + ((g ^ (rr & 7)) << 3);
        af0[mi] = *(const short8*)&As0[idx];
        af1[mi] = *(const short8*)&As1[idx];
      }
#pragma unroll
      for (int nj = 0; nj < 2; ++nj) {
        int rr = wn + (nj << 4) + l16;
        int g = (kk << 2) + quad;
        int idx = rr * 64 + ((g ^ (rr & 7)) << 3);
        bf0[nj] = *(const short8*)&Bs0[idx];
        bf1[nj] = *(const short8*)&Bs1[idx];
      }
#pragma unroll
      for (int mi = 0; mi < 4; ++mi)
#pragma unroll
        for (int nj = 0; nj < 2; ++nj) {
          acc[mi][nj] = __builtin_amdgcn_mfma_f32_16x16x32_bf16(af1[mi], bf0[nj], acc[mi][nj], 0, 0, 0);
          acc[mi][nj] = __builtin_amdgcn_mfma_f32_16x16x32_bf16(af0[mi], bf1[nj], acc[mi][nj], 0, 0, 0);
          acc[mi][nj] = __builtin_amdgcn_mfma_f32_16x16x32_bf16(af0[mi], bf0[nj], acc[mi][nj], 0, 0, 0);
        }
    }
    __syncthreads();
  }
#pragma unroll
  for (int mi = 0; mi < 4; ++mi)
#pragma unroll
    for (int nj = 0; nj < 2; ++nj)
#pragma unroll
      for (int r = 0; r < 4; ++r) {
        int mm = m0 + wm + (mi << 4) + (quad << 2) + r;
        int nn = n0 + wn + (nj << 4) + l16;
        float v = acc[mi][nj][r];
        if (BF16OUT)
          ((ushort*)CBase)[(size_t)mm * N + nn] = f2b(v);
        else
          ((float*)CBase)[(size_t)mm * N + nn] = v;
      }
}

// ======== 128x128-tile bf16 x bf16 GEMM (final projection), fp32 out ========
__global__ __launch_bounds__(512) void gemm128_b16(const ushort* __restrict__ A,
                                                   const ushort* __restrict__ Bt,
                                                   float* __restrict__ C) {
  const int N = 2048, K = 2048;
  int m0 = blockIdx.y << 7, n0 = blockIdx.x << 7;
  __shared__ ushort As[8192], Bs[8192];
  int tid = threadIdx.x;
  int row = tid >> 2, c0 = (tid & 3) << 4;
  int sw = row & 7, g0 = c0 >> 3;
  int dst0 = row * 64 + ((g0 ^ sw) << 3);
  int dst1 = row * 64 + (((g0 + 1) ^ sw) << 3);
  const ushort* aptr = A + (size_t)(m0 + row) * K + c0;
  const ushort* bptr = Bt + (size_t)(n0 + row) * K + c0;
  int lane = tid & 63, wave = tid >> 6;
  int l16 = lane & 15, quad = lane >> 4;
  int wm = (wave & 1) << 6, wn = (wave >> 1) << 5;
  f32x4 acc[4][2] = {};
  for (int k0 = 0; k0 < K; k0 += 64) {
    uint4 av0 = *(const uint4*)(aptr + k0), av1 = *(const uint4*)(aptr + k0 + 8);
    uint4 bv0 = *(const uint4*)(bptr + k0), bv1 = *(const uint4*)(bptr + k0 + 8);
    *(uint4*)&As[dst0] = av0;  *(uint4*)&As[dst1] = av1;
    *(uint4*)&Bs[dst0] = bv0;  *(uint4*)&Bs[dst1] = bv1;
    __syncthreads();
#pragma unroll
    for (int kk = 0; kk < 2; ++kk) {
      short8 af[4], bf[2];
#pragma unroll
      for (int mi = 0; mi < 4; ++mi) {
        int rr = wm + (mi << 4) + l16;
        int g = (kk << 2) + quad;
        af[mi] = *(const short8*)&As[rr * 64 + ((g ^ (rr & 7)) << 3)];
      }
#pragma unroll
      for (int nj = 0; nj < 2; ++nj) {
        int rr = wn + (nj << 4) + l16;
        int g = (kk << 2) + quad;
        bf[nj] = *(const short8*)&Bs[rr * 64 + ((g ^ (rr & 7)) << 3)];
      }
#pragma unroll
      for (int mi = 0; mi < 4; ++mi)
#pragma unroll
        for (int nj = 0; nj < 2; ++nj)
          acc[mi][nj] = __builtin_amdgcn_mfma_f32_16x16x32_bf16(af[mi], bf[nj], acc[mi][nj], 0, 0, 0);
    }
    __syncthreads();
  }
#pragma unroll
  for (int mi = 0; mi < 4; ++mi)
#pragma unroll
    for (int nj = 0; nj < 2; ++nj)
#pragma unroll
      for (int r = 0; r < 4; ++r) {
        int mm = m0 + wm + (mi << 4) + (quad << 2) + r;
        int nn = n0 + wn + (nj << 4) + l16;
        C[(size_t)mm * N + nn] = acc[mi][nj][r];
      }
}

// ------ 64x64-tile 6-term GEMM with PRE-SPLIT A (3 bf16 planes): pure-load staging (G only) ------
__global__ __launch_bounds__(256) void gemm_pre(const ushort* __restrict__ A0,
                                                const ushort* __restrict__ A1,
                                                const ushort* __restrict__ A2,
                                                const ushort* __restrict__ B0,
                                                const ushort* __restrict__ B1,
                                                const ushort* __restrict__ B2,
                                                float* __restrict__ C) {
  const int N = 2048, K = 2048;
  int m0 = blockIdx.y << 6, n0 = blockIdx.x << 6;
  __shared__ ushort As0[4096], As1[4096], As2[4096];
  __shared__ ushort Bs0[4096], Bs1[4096], Bs2[4096];
  int tid = threadIdx.x;
  int row = tid >> 2, c0 = (tid & 3) << 4;
  int sw = row & 7;
  int g0 = c0 >> 3;
  int dst0 = row * 64 + ((g0 ^ sw) << 3);
  int dst1 = row * 64 + (((g0 + 1) ^ sw) << 3);
  const ushort* a0p = A0 + (size_t)(m0 + row) * K + c0;
  const ushort* a1p = A1 + (size_t)(m0 + row) * K + c0;
  const ushort* a2p = A2 + (size_t)(m0 + row) * K + c0;
  const ushort* b0p = B0 + (size_t)(n0 + row) * K + c0;
  const ushort* b1p = B1 + (size_t)(n0 + row) * K + c0;
  const ushort* b2p = B2 + (size_t)(n0 + row) * K + c0;
  int lane = tid & 63, wave = tid >> 6;
  int l16 = lane & 15, quad = lane >> 4;
  int wm = (wave & 1) << 5, wn = (wave >> 1) << 5;
  f32x4 acc[2][2] = {};
  for (int k0 = 0; k0 < K; k0 += 64) {
    uint4 a00 = *(const uint4*)(a0p + k0), a01 = *(const uint4*)(a0p + k0 + 8);
    uint4 a10 = *(const uint4*)(a1p + k0), a11 = *(const uint4*)(a1p + k0 + 8);
    uint4 a20 = *(const uint4*)(a2p + k0), a21 = *(const uint4*)(a2p + k0 + 8);
    uint4 b00 = *(const uint4*)(b0p + k0), b01 = *(const uint4*)(b0p + k0 + 8);
    uint4 b10 = *(const uint4*)(b1p + k0), b11 = *(const uint4*)(b1p + k0 + 8);
    uint4 b20 = *(const uint4*)(b2p + k0), b21 = *(const uint4*)(b2p + k0 + 8);
    *(uint4*)&As0[dst0] = a00;  *(uint4*)&As0[dst1] = a01;
    *(uint4*)&As1[dst0] = a10;  *(uint4*)&As1[dst1] = a11;
    *(uint4*)&As2[dst0] = a20;  *(uint4*)&As2[dst1] = a21;
    *(uint4*)&Bs0[dst0] = b00;  *(uint4*)&Bs0[dst1] = b01;
    *(uint4*)&Bs1[dst0] = b10;  *(uint4*)&Bs1[dst1] = b11;
    *(uint4*)&Bs2[dst0] = b20;  *(uint4*)&Bs2[dst1] = b21;
    __syncthreads();
#pragma unroll
    for (int kk = 0; kk < 2; ++kk) {
      short8 af0[2], af1[2], af2[2], bf0[2], bf1[2], bf2[2];
#pragma unroll
      for (int mi = 0; mi < 2; ++mi) {
        int rr = wm + (mi << 4) + l16;
        int g = (kk << 2) + quad;
        int idx = rr * 64 + ((g ^ (rr & 7)) << 3);
        af0[mi] = *(const short8*)&As0[idx];
        af1[mi] = *(const short8*)&As1[idx];
        af2[mi] = *(const short8*)&As2[idx];
      }
#pragma unroll
      for (int nj = 0; nj < 2; ++nj) {
        int rr = wn + (nj << 4) + l16;
        int g = (kk << 2) + quad;
        int idx = rr * 64 + ((g ^ (rr & 7)) << 3);
        bf0[nj] = *(const short8*)&Bs0[idx];
        bf1[nj] = *(const short8*)&Bs1[idx];
        bf2[nj] = *(const short8*)&Bs2[idx];
      }
#pragma unroll
      for (int mi = 0; mi < 2; ++mi)
#pragma unroll
        for (int nj = 0; nj < 2; ++nj) {
          acc[mi][nj] = __builtin_amdgcn_mfma_f32_16x16x32_bf16(af2[mi], bf0[nj], acc[mi][nj], 0, 0, 0);
          acc[mi][nj] = __builtin_amdgcn_mfma_f32_16x16x32_bf16(af0[mi], bf2[nj], acc[mi][nj], 0, 0, 0);
          acc[mi][nj] = __builtin_amdgcn_mfma_f32_16x16x32_bf16(af1[mi], bf1[nj], acc[mi][nj], 0, 0, 0);
          acc[mi][nj] = __builtin_amdgcn_mfma_f32_16x16x32_bf16(af1[mi], bf0[nj], acc[mi][nj], 0, 0, 0);
          acc[mi][nj] = __builtin_amdgcn_mfma_f32_16x16x32_bf16(af0[mi], bf1[nj], acc[mi][nj], 0, 0, 0);
          acc[mi][nj] = __builtin_amdgcn_mfma_f32_16x16x32_bf16(af0[mi], bf0[nj], acc[mi][nj], 0, 0, 0);
        }
    }
    __syncthreads();
  }
#pragma unroll
  for (int mi = 0; mi < 2; ++mi)
#pragma unroll
    for (int nj = 0; nj < 2; ++nj)
#pragma unroll
      for (int r = 0; r < 4; ++r) {
        int mm = m0 + wm + (mi << 4) + (quad << 2) + r;
        int nn = n0 + wn + (nj << 4) + l16;
        C[(size_t)mm * N + nn] = acc[mi][nj][r];
      }
}

// ---------------- clock pre-activation: x @ W_clock (2048x16), fp32 ----------------
__global__ __launch_bounds__(64) void wclock_k(const float* __restrict__ x,
                                               const float* __restrict__ Wc,
                                               float* __restrict__ out) {
  int m = blockIdx.x, lane = threadIdx.x;
  const float* xr = x + (size_t)m * Dd;
  float acc[16];
#pragma unroll
  for (int h = 0; h < 16; ++h) acc[h] = 0.f;
  for (int k = lane; k < Dd; k += 64) {
    float xv = xr[k];
    const float* wr = Wc + k * 16;
#pragma unroll
    for (int h = 0; h < 16; ++h) acc[h] += xv * wr[h];
  }
#pragma unroll
  for (int h = 0; h < 16; ++h) {
#pragma unroll
    for (int off = 32; off; off >>= 1) acc[h] += __shfl_down(acc[h], off);
  }
  if (lane == 0) {
    float* o = out + (size_t)m * 16;
#pragma unroll
    for (int h = 0; h < 16; ++h) o[h] = acc[h];
  }
}

// ---------------- per-chunk max of p = (x@W_p) + log(clock) over 256-t chunks ----------------
__global__ __launch_bounds__(128) void pmaxchunk_k(const float* __restrict__ Pf,
                                                   const float* __restrict__ cpre,
                                                   float* __restrict__ pmaxc) {
  int bh = blockIdx.x, ch = blockIdx.y, d = threadIdx.x;
  int b = bh >> 4, h = bh & 15;
  float mx = -1e30f;
  int t0 = ch << 8;
  for (int t = t0; t < t0 + 256; ++t) {
    float pr = Pf[((size_t)(b * Tt + t)) * Dd + h * 128 + d];
    float c = softplusf(cpre[(b * Tt + t) * Hh + h]) + 1e-6f;
    mx = fmaxf(mx, pr + logf(c));
  }
  pmaxc[(size_t)(bh * 8 + ch) * 128 + d] = mx;
}

// ======== blocked scan, stage 1: elementwise (rope, pe, gj, clock) + per-32t chunk sums ========
__global__ __launch_bounds__(128) void scan_ew_k(float* planes,
                                                 const float* __restrict__ cpre,
                                                 const float* __restrict__ pmaxc,
                                                 float* __restrict__ clockv,
                                                 float* __restrict__ sum_pe,
                                                 float* __restrict__ sum_gj,
                                                 float* __restrict__ sum_ck) {
  int ch = blockIdx.x, bh = blockIdx.y;
  int b = bh >> 4, h = bh & 15, d = threadIdx.x;
  float* Qf = planes;
  float* Kf = planes + (size_t)MD;
  float* Gf = planes + 2 * (size_t)MD;
  float* Pf = planes + 3 * (size_t)MD;
  float invf = (float)exp(-((double)((d & 63) * 2) / 128.0) * log(10000.0));
  float pmax = -1e30f;
#pragma unroll
  for (int c = 0; c < 8; ++c) pmax = fmaxf(pmax, pmaxc[(size_t)(bh * 8 + c) * 128 + d]);
  float s_pe = 0.f, s_gj = 0.f, s_ck = 0.f;
  int t0 = ch << 5;
#pragma unroll 4
  for (int i = 0; i < 32; ++i) {
    int t = t0 + i;
    size_t off = ((size_t)(b * Tt + t)) * Dd + h * 128 + d;
    float qv = Qf[off], kv = Kf[off], pv = Pf[off], gv = Gf[off];
    float clock = softplusf(cpre[(b * Tt + t) * Hh + h]) + 1e-6f;
    float ang = (float)t * invf;
    float c_ = cosf(ang), s_ = sinf(ang);
    float qp = __shfl_xor(qv, 1);
    float kp = __shfl_xor(kv, 1);
    float qrot = (d & 1) ? qp : -qp;
    float krot = (d & 1) ? kp : -kp;
    float qr = qv * c_ + qrot * s_;
    float kr = kv * c_ + krot * s_;
    float pe = expf(pv + logf(clock) - pmax);
    s_pe += pe;
    float gj = -softplusf(gv) * clock;
    s_gj += gj;
    Qf[off] = qr;
    Kf[off] = kr;
    Gf[off] = gj;     // gj for now; scan_apply_k turns it into e
    Pf[off] = pe;
    if (d == 0) {
      clockv[bh * Tt + t] = clock;
      s_ck += clock;
    }
  }
  size_t so = (size_t)(bh * 64 + ch) * 128 + d;
  sum_pe[so] = s_pe;
  sum_gj[so] = s_gj;
  if (d == 0) sum_ck[bh * 64 + ch] = s_ck;
}

// ======== blocked scan, stage 2: exclusive scan of chunk sums (pcs_cp falls out directly) ========
__global__ __launch_bounds__(128) void scan_off_k(const float* __restrict__ sum_pe,
                                                  const float* __restrict__ sum_gj,
                                                  const float* __restrict__ sum_ck,
                                                  float* __restrict__ pcs_cp,
                                                  float* __restrict__ goff,
                                                  float* __restrict__ coff) {
  int bh = blockIdx.x, d = threadIdx.x;
  float ppe = 0.f, pgj = 0.f, pck = 0.f;
  for (int c = 0; c < 64; ++c) {
    size_t o = (size_t)(bh * 64 + c) * 128 + d;
    pcs_cp[o] = ppe;
    goff[o] = pgj;
    ppe += sum_pe[o];
    pgj += sum_gj[o];
    if (d == 0) { coff[bh * 64 + c] = pck; pck += sum_ck[bh * 64 + c]; }
  }
}

// ======== blocked scan, stage 3: within-chunk gcs -> e (Gf), and ccsv ========
__global__ __launch_bounds__(128) void scan_apply_k(float* planes,
                                                    const float* __restrict__ goff,
                                                    const float* __restrict__ coff,
                                                    const float* __restrict__ clockv,
                                                    float* __restrict__ ccsv) {
  int ch = blockIdx.x, bh = blockIdx.y;
  int b = bh >> 4, h = bh & 15, d = threadIdx.x;
  float* Gf = planes + 2 * (size_t)MD;
  float g = goff[(size_t)(bh * 64 + ch) * 128 + d];
  float ccs = (d == 0) ? coff[bh * 64 + ch] : 0.f;
  int t0 = ch << 5;
#pragma unroll 4
  for (int i = 0; i < 32; ++i) {
    int t = t0 + i;
    size_t off = ((size_t)(b * Tt + t)) * Dd + h * 128 + d;
    float gj = Gf[off];
    g += gj;
    float e = expf(fminf(fmaxf(g, -50.f), 40.f));
    Gf[off] = e;
    if (d == 0) {
      ccs += clockv[bh * Tt + t];
      ccsv[bh * Tt + t] = ccs;
    }
  }
}

// ---------------- MFMA flash attention: 128 q-rows/block, 8 waves x 16 rows ----------------
__global__ __launch_bounds__(512, 2) void attn_mfma_k(const float* __restrict__ planes,
                                                      const ushort* __restrict__ Vb,
                                                      const float* __restrict__ clockv,
                                                      const float* __restrict__ ccsv,
                                                      const float* __restrict__ pcs_cp,
                                                      ushort* __restrict__ attnout) {
  __shared__ float smemf[18432];            // 72 KB -> 2 blocks/CU, 16 waves/CU
  ushort* Khi = (ushort*)smemf;             // [32 keys][384 dims] swizzled  @0      (24576 B)
  ushort* Klo = Khi + 12288;                //                              @24576  (24576 B)
  ushort* Vsm = Khi + 24576;                // [32 keys][128 dims] 4x16-subtiled @49152 (8192 B)
  unsigned* Pu = (unsigned*)(smemf + 14336);// 8 waves x [16 rows][32 keys] u32 @57344 (16384 B)
  float* pcsL = smemf;                      // phase alias @0: [64][128] f32 (32 KB)
  ushort* qscr = (ushort*)(smemf + 8192);   // phase alias @32768: 4 x 8 KB

  int tid = threadIdx.x;
  int lane = tid & 63, wave = tid >> 6;     // wave 0..7
  int l15 = lane & 15, qd = lane >> 4;
  int qt0 = blockIdx.x << 7;                // 128 q rows per block
  int bh = blockIdx.y, b = bh >> 4, h = bh & 15;
  const float* Qf = planes;
  const float* Kf = planes + (size_t)MD;
  const float* Ef = planes + 2 * (size_t)MD;
  const float* Pe = planes + 3 * (size_t)MD;
  size_t pbase = ((size_t)b * Tt) * Dd + h * 128;

  // ---- Q prep in 2 rounds: rows 0..63 (waves 0..3), rows 64..127 (waves 4..7) ----
  short8 qh[12], ql[12];
  int wl = wave & 3;
  int rloc = lane >> 2;                     // 0..15, row within wave tile
  {
    ushort* sh = qscr + (wl << 12);         // [16][128] hi ushort (4 KB)
    ushort* sl = sh + 2048;                 // lo (4 KB)
#pragma unroll
    for (int rd = 0; rd < 2; ++rd) {
      // phase A: pcs replay for this round's 64 rows (256 threads; chunk==32 rows)
      if (tid < 256) {
        int d = tid & 127, seg = tid >> 7;
        int rbase = (rd << 6) + (seg << 5);
        float pcs = pcs_cp[((size_t)bh * 64 + (qt0 >> 5) + (rd << 1) + seg) * 128 + d];
        for (int i = 0; i < 32; ++i) {
          pcs += Pe[pbase + (size_t)(qt0 + rbase + i) * Dd + d];
          pcsL[((seg << 5) + i) * 128 + d] = pcs;
        }
      }
      __syncthreads();
      int part = ((wave >> 2) == rd);
      int grow = qt0 + (rd << 6) + (wl << 4) + rloc;
      float ccsr = __builtin_amdgcn_rcpf(ccsv[bh * Tt + grow]);
      size_t goffq = pbase + (size_t)grow * Dd;
#pragma unroll
      for (int cd = 0; cd < 3; ++cd) {
        __syncthreads();
        if (part) {
#pragma unroll
          for (int j = 0; j < 4; ++j) {
            int d0 = ((lane & 3) << 5) + (j << 3);   // 8 dims
            float qv[8], mv[8];
            *(float4*)&qv[0] = *(const float4*)(Qf + goffq + d0);
            *(float4*)&qv[4] = *(const float4*)(Qf + goffq + d0 + 4);
            if (cd == 0) {
              *(float4*)&mv[0] = *(const float4*)&pcsL[((wl << 4) + rloc) * 128 + d0];
              *(float4*)&mv[4] = *(const float4*)&pcsL[((wl << 4) + rloc) * 128 + d0 + 4];
#pragma unroll
              for (int i = 0; i < 8; ++i) qv[i] = qv[i] * __builtin_amdgcn_rcpf(mv[i] + 1e-8f);
            } else if (cd == 1) {
              *(float4*)&mv[0] = *(const float4*)(Ef + goffq + d0);
              *(float4*)&mv[4] = *(const float4*)(Ef + goffq + d0 + 4);
#pragma unroll
              for (int i = 0; i < 8; ++i) qv[i] = qv[i] * mv[i];
            } else {
#pragma unroll
              for (int i = 0; i < 8; ++i) qv[i] = qv[i] * ccsr;
            }
            ushort hi8[8], lo8[8];
#pragma unroll
            for (int i = 0; i < 8; ++i) {
              ushort a = f2b(qv[i]); hi8[i] = a; lo8[i] = f2b(qv[i] - b2f(a));
            }
            int g = ((lane & 3) << 2) + j;          // dim group 0..15
            int phys = (g & 8) | ((g ^ rloc) & 7);
            *(uint4*)&sh[rloc * 128 + (phys << 3)] = *(uint4*)hi8;
            *(uint4*)&sl[rloc * 128 + (phys << 3)] = *(uint4*)lo8;
          }
        }
        __syncthreads();
        if (part) {
#pragma unroll
          for (int ksl = 0; ksl < 4; ++ksl) {
            int g = (ksl << 2) + qd;
            int phys = (g & 8) | ((g ^ l15) & 7);
            qh[(cd << 2) + ksl] = *(const short8*)&sh[l15 * 128 + (phys << 3)];
            ql[(cd << 2) + ksl] = *(const short8*)&sl[l15 * 128 + (phys << 3)];
          }
        }
      }
      __syncthreads();                      // pcsL/qscr reuse (and Khi alias) safe
    }
  }

  // ---- main loop over 64 key-tiles of 32 ----
  float mi4[4], li4[4];
  f32x4 acc_pv[8] = {};
#pragma unroll
  for (int r = 0; r < 4; ++r) { mi4[r] = -1e30f; li4[r] = 0.f; }
  const float scl = 0.05103103630798287f;   // 1/sqrt(384)
  const ushort* vbase = Vb + pbase;
  unsigned* PuW = Pu + (wave << 9);         // per-wave 2 KB
  unsigned VsmA = (unsigned)(size_t)Vsm;    // LDS byte address (low 32 bits of flat)
  int kk = tid >> 4;                        // key 0..31 (staging role)
  int kdb = tid & 15;                       // 8-dim block (staging role)

  for (int st = 0; st < 64; ++st) {
    int s0 = st << 5;
    __syncthreads();                        // all reads of K/V tile (st-1) done
    // ---- stage K (3 cat slots, RTZ-hi + exact-residual-lo split) + V tile (4x16 subtiles) ----
    {
      size_t roff = pbase + (size_t)(s0 + kk) * Dd + (kdb << 3);
      float ck = clockv[bh * Tt + s0 + kk];
      float kv[8], pev[8], ev[8];
      *(float4*)&kv[0] = *(const float4*)(Kf + roff);
      *(float4*)&kv[4] = *(const float4*)(Kf + roff + 4);
      *(float4*)&pev[0] = *(const float4*)(Pe + roff);
      *(float4*)&pev[4] = *(const float4*)(Pe + roff + 4);
      *(float4*)&ev[0] = *(const float4*)(Ef + roff);
      *(float4*)&ev[4] = *(const float4*)(Ef + roff + 4);
#pragma unroll
      for (int slot = 0; slot < 3; ++slot) {
        float val[8];
        if (slot == 0) {
#pragma unroll
          for (int i = 0; i < 8; ++i) val[i] = kv[i] * pev[i];
        } else if (slot == 1) {
#pragma unroll
          for (int i = 0; i < 8; ++i) val[i] = kv[i] * __builtin_amdgcn_rcpf(ev[i] + 1e-8f);
        } else {
#pragma unroll
          for (int i = 0; i < 8; ++i) val[i] = kv[i] * ck;
        }
        unsigned ub[8], ul[8];
#pragma unroll
        for (int i = 0; i < 8; ++i) {
          union { float f; unsigned u; } c; c.f = val[i];
          ub[i] = c.u;
          union { unsigned u; float f; } hm; hm.u = c.u & 0xffff0000u;
          union { float f; unsigned u; } lr; lr.f = val[i] - hm.f;
          ul[i] = lr.u;
        }
        uint4 hi4, lo4;
        hi4.x = (ub[0] >> 16) | (ub[1] & 0xffff0000u);
        hi4.y = (ub[2] >> 16) | (ub[3] & 0xffff0000u);
        hi4.z = (ub[4] >> 16) | (ub[5] & 0xffff0000u);
        hi4.w = (ub[6] >> 16) | (ub[7] & 0xffff0000u);
        lo4.x = (ul[0] >> 16) | (ul[1] & 0xffff0000u);
        lo4.y = (ul[2] >> 16) | (ul[3] & 0xffff0000u);
        lo4.z = (ul[4] >> 16) | (ul[5] & 0xffff0000u);
        lo4.w = (ul[6] >> 16) | (ul[7] & 0xffff0000u);
        int g = (slot << 4) + kdb;
        int phys = (g & ~7) | ((g ^ kk) & 7);
        *(uint4*)&Khi[kk * 384 + (phys << 3)] = hi4;
        *(uint4*)&Klo[kk * 384 + (phys << 3)] = lo4;
      }
      // V: subtile layout
      const ushort* vsrc = vbase + (size_t)(s0 + kk) * Dd + (kdb << 3);
      int vbyte = ((kdb >> 1) << 10) + (((kk >> 2) & 1) << 9) + ((kk >> 3) << 7) +
                  ((kk & 3) << 5) + ((kdb & 1) << 4);
      *(uint4*)((char*)Vsm + vbyte) = *(const uint4*)vsrc;
    }
    __syncthreads();
    // ---- QK^T: 2-term split-bf16 MFMA (3 terms, smallest first) ----
    f32x4 acc0 = {}, acc1 = {};
#pragma unroll
    for (int ks = 0; ks < 12; ++ks) {
      int g = (ks << 2) + qd;
      int p0i = (g & ~7) | ((g ^ l15) & 7);
      int p1i = (g & ~7) | ((g ^ (16 + l15)) & 7);
      short8 b0h = *(const short8*)&Khi[l15 * 384 + (p0i << 3)];
      short8 b0l = *(const short8*)&Klo[l15 * 384 + (p0i << 3)];
      short8 b1h = *(const short8*)&Khi[(16 + l15) * 384 + (p1i << 3)];
      short8 b1l = *(const short8*)&Klo[(16 + l15) * 384 + (p1i << 3)];
      acc0 = __builtin_amdgcn_mfma_f32_16x16x32_bf16(ql[ks], b0h, acc0, 0, 0, 0);
      acc0 = __builtin_amdgcn_mfma_f32_16x16x32_bf16(qh[ks], b0l, acc0, 0, 0, 0);
      acc0 = __builtin_amdgcn_mfma_f32_16x16x32_bf16(qh[ks], b0h, acc0, 0, 0, 0);
      acc1 = __builtin_amdgcn_mfma_f32_16x16x32_bf16(ql[ks], b1h, acc1, 0, 0, 0);
      acc1 = __builtin_amdgcn_mfma_f32_16x16x32_bf16(qh[ks], b1l, acc1, 0, 0, 0);
      acc1 = __builtin_amdgcn_mfma_f32_16x16x32_bf16(qh[ks], b1h, acc1, 0, 0, 0);
    }
    // ---- online softmax; P -> Pu (hi/lo packed) ----
#pragma unroll
    for (int r = 0; r < 4; ++r) {
      float sa = acc0[r] * scl, sb = acc1[r] * scl;
      float mx = fmaxf(sa, sb);
#pragma unroll
      for (int m = 1; m < 16; m <<= 1) mx = fmaxf(mx, __shfl_xor(mx, m));
      float mn = fmaxf(mi4[r], mx);
      float al = expf(mi4[r] - mn);
      float p0 = expf(sa - mn), p1 = expf(sb - mn);
      float rs = p0 + p1;
#pragma unroll
      for (int m = 1; m < 16; m <<= 1) rs += __shfl_xor(rs, m);
      li4[r] = li4[r] * al + rs;
      mi4[r] = mn;
#pragma unroll
      for (int n0 = 0; n0 < 8; ++n0) acc_pv[n0][r] *= al;
      int R = (qd << 2) + r;
      {
        union { float f; unsigned u; } c0, c1; c0.f = p0; c1.f = p1;
        union { unsigned u; float f; } m0_, m1_;
        m0_.u = c0.u & 0xffff0000u; m1_.u = c1.u & 0xffff0000u;
        union { float f; unsigned u; } d0_, d1_;
        d0_.f = p0 - m0_.f; d1_.f = p1 - m1_.f;
        unsigned u0 = (c0.u >> 16) | (d0_.u & 0xffff0000u);
        unsigned u1 = (c1.u >> 16) | (d1_.u & 0xffff0000u);
        int r7 = R & 7;
        char* pb = (char*)PuW + (R << 7) + ((l15 & 3) << 2);
        *(unsigned*)(pb + (((l15 >> 2) ^ r7) << 4)) = u0;
        *(unsigned*)(pb + ((((l15 >> 2) + 4) ^ r7) << 4)) = u1;
      }
    }
    // ---- PV via MFMA ----
    {
      unsigned pw[8];
      {
        const char* pb = (const char*)PuW + l15 * 128;
        uint4 w0 = *(const uint4*)(pb + ((((qd << 1)) ^ (l15 & 7)) << 4));
        uint4 w1 = *(const uint4*)(pb + ((((qd << 1) | 1) ^ (l15 & 7)) << 4));
        pw[0] = w0.x; pw[1] = w0.y; pw[2] = w0.z; pw[3] = w0.w;
        pw[4] = w1.x; pw[5] = w1.y; pw[6] = w1.z; pw[7] = w1.w;
      }
      union { unsigned u[4]; short8 s; } uph, upl;
#pragma unroll
      for (int i = 0; i < 4; ++i) {
        uph.u[i] = (pw[2 * i] & 0xffffu) | (pw[2 * i + 1] << 16);
        upl.u[i] = (pw[2 * i] >> 16) | (pw[2 * i + 1] & 0xffff0000u);
      }
      short4v tv[16];
#pragma unroll
      for (int n0 = 0; n0 < 8; ++n0) {
        unsigned a0 = VsmA + (n0 << 10) + (lane << 3);
        tv[2 * n0] = tr16(a0);
        tv[2 * n0 + 1] = tr16(a0 + 512);
      }
      asm volatile("s_waitcnt lgkmcnt(0)" ::: "memory");
      __builtin_amdgcn_sched_barrier(0);
#pragma unroll
      for (int n0 = 0; n0 < 8; ++n0) {
        short8 bv = __builtin_shufflevector(tv[2 * n0], tv[2 * n0 + 1], 0, 1, 2, 3, 4, 5, 6, 7);
        acc_pv[n0] = __builtin_amdgcn_mfma_f32_16x16x32_bf16(uph.s, bv, acc_pv[n0], 0, 0, 0);
        acc_pv[n0] = __builtin_amdgcn_mfma_f32_16x16x32_bf16(upl.s, bv, acc_pv[n0], 0, 0, 0);
      }
    }
  }
  // ---- epilogue: normalize, bf16 out ----
#pragma unroll
  for (int r = 0; r < 4; ++r) {
    float inv = 1.f / li4[r];
    int trow = qt0 + (wave << 4) + (qd << 2) + r;
    ushort* orow = attnout + ((size_t)(b * Tt + trow)) * Dd + h * 128 + l15;
#pragma unroll
    for (int n0 = 0; n0 < 8; ++n0)
      orow[n0 << 4] = f2b(acc_pv[n0][r] * inv);
  }
}

extern "C" void kernel_launch(void* const* d_in, const int* in_sizes, int n_in,
                              void* d_out, int out_size, void* d_ws, size_t ws_size,
                              hipStream_t stream) {
  const float* x = (const float*)d_in[0];
  const float* Wq = (const float*)d_in[1];
  const float* Wk = (const float*)d_in[2];
  const float* Wv = (const float*)d_in[3];
  const float* Wg = (const float*)d_in[4];
  const float* Wp = (const float*)d_in[5];
  const float* Wclk = (const float*)d_in[6];
  const float* Wc = (const float*)d_in[7];

  // ---- workspace layout (~178 MiB) ----
  float* planes = (float*)d_ws;                       // 4 * MD fp32: qr | kr | e | pe
  float* Aq = planes;
  float* Bk = planes + (size_t)MD;
  float* Ce = planes + 2 * (size_t)MD;
  float* Dp = planes + 3 * (size_t)MD;
  ushort* Vb = (ushort*)(planes + 4 * (size_t)MD);    // MD bf16
  float* cpre = (float*)(Vb + (size_t)MD);            // 65536
  float* clockv = cpre + 65536;                       // 65536
  float* ccsv = clockv + 65536;                       // 65536
  float* pmaxc = ccsv + 65536;                        // 32768
  float* pcs_cp = pmaxc + 32768;                      // 32*64*128 = 262144
  ushort* Wt0 = (ushort*)(pcs_cp + 262144);           // 3 x Dd*Dd bf16 (projection phase)
  ushort* Wt1 = Wt0 + (size_t)Dd * Dd;
  ushort* Wt2 = Wt1 + (size_t)Dd * Dd;
  ushort* attnout = Wt0;                              // reuse Wt region (dead after projections)
  ushort* WcT0 = (ushort*)Ce;                         // post-attention: reuse e-plane for Wc^T
  // x-split planes (48 MB) live in Dp (32 MB) + Vb (16 MB) — dead until P/V projections.
  ushort* xs0 = (ushort*)Dp;                          // MD bf16
  ushort* xs1 = xs0 + (size_t)MD;                     // MD bf16
  ushort* xs2 = (ushort*)Vb;                          // MD bf16
  // scan temporaries live in the Wt2 region
  float* sum_pe = (float*)Wt2;                        // 262144
  float* sum_gj = sum_pe + 262144;                    // 262144
  float* goff_  = sum_gj + 262144;                    // 262144
  float* sum_ck = goff_ + 262144;                     // 2048
  float* coff_  = sum_ck + 2048;                      // 2048

  size_t needed = (size_t)((char*)(Wt2 + (size_t)Dd * Dd) - (char*)d_ws);
  if (ws_size < needed) return;  // diagnostic: absmax ~= 4.69 => ws too small

  dim3 tg(Dd / 64, Dd / 64);
  dim3 g128(Dd / 128, Mm / 128), gg(Dd / 64, Mm / 64);

  // x split planes (once)
  xsplit_k<<<dim3(MD / 8 / 256), 256, 0, stream>>>(x, xs0, xs1, xs2);

  // Q, K projections: 3-term, 128x128 tile (pre-split A)
  split_transposeN<2><<<tg, 256, 0, stream>>>(Wq, Wt0, Wt1, nullptr);
  gemm128_pre2<<<g128, 512, 0, stream>>>(xs0, xs1, Wt0, Wt1, Aq);
  split_transposeN<2><<<tg, 256, 0, stream>>>(Wk, Wt0, Wt1, nullptr);
  gemm128_pre2<<<g128, 512, 0, stream>>>(xs0, xs1, Wt0, Wt1, Bk);
  // G projection: keep 6-term 64x64 (cumsum-exponent sensitivity)
  split_transposeN<3><<<tg, 256, 0, stream>>>(Wg, Wt0, Wt1, Wt2);
  gemm_pre<<<gg, 256, 0, stream>>>(xs0, xs1, xs2, Wt0, Wt1, Wt2, Ce);
  // P, V projections: 3-term 128x128, direct-x path (outputs overwrite dead xs planes)
  split_transposeN<2><<<tg, 256, 0, stream>>>(Wp, Wt0, Wt1, nullptr);
  gemm128_split2<0><<<g128, 512, 0, stream>>>(x, Wt0, Wt1, (void*)Dp);
  split_transposeN<2><<<tg, 256, 0, stream>>>(Wv, Wt0, Wt1, nullptr);
  gemm128_split2<1><<<g128, 512, 0, stream>>>(x, Wt0, Wt1, (void*)Vb);

  // clock pre-activation, chunked p_max
  wclock_k<<<dim3(Mm), dim3(64), 0, stream>>>(x, Wclk, cpre);
  pmaxchunk_k<<<dim3(Bb * Hh, 8), dim3(128), 0, stream>>>(Dp, cpre, pmaxc);

  // blocked scan
  scan_ew_k<<<dim3(64, Bb * Hh), dim3(128), 0, stream>>>(planes, cpre, pmaxc, clockv,
                                                         sum_pe, sum_gj, sum_ck);
  scan_off_k<<<dim3(Bb * Hh), dim3(128), 0, stream>>>(sum_pe, sum_gj, sum_ck,
                                                      pcs_cp, goff_, coff_);
  scan_apply_k<<<dim3(64, Bb * Hh), dim3(128), 0, stream>>>(planes, goff_, coff_, clockv, ccsv);

  // MFMA flash attention -> attnout
  attn_mfma_k<<<dim3(Tt / 128, Bb * Hh), dim3(512), 0, stream>>>(planes, Vb, clockv, ccsv, pcs_cp, attnout);

  // Wc^T (1 plane), then final GEMM (128x128) -> fp32 d_out
  split_transposeN<1><<<tg, 256, 0, stream>>>(Wc, WcT0, nullptr, nullptr);
  gemm128_b16<<<g128, 512, 0, stream>>>(attnout, WcT0, (float*)d_out);
}

// Round 8
// 1533.429 us; speedup vs baseline: 1.5112x; 1.1167x over previous
//
#include <hip/hip_runtime.h>

typedef unsigned short ushort;
typedef __attribute__((ext_vector_type(8))) short short8;
typedef __attribute__((ext_vector_type(4))) short short4v;
typedef __attribute__((ext_vector_type(4))) float f32x4;

#define Bb 2
#define Tt 2048
#define Dd 2048
#define Hh 16
#define Mm 4096                 // B*T
#define MD 8388608u             // Mm*Dd

__device__ __forceinline__ float b2f(ushort u) {
  union { unsigned int ui; float f; } v; v.ui = ((unsigned int)u) << 16; return v.f;
}
__device__ __forceinline__ ushort f2b(float f) {
  union { float f; unsigned int u; } v; v.f = f;
  unsigned int r = (v.u + 0x7fffu + ((v.u >> 16) & 1u)) >> 16;
  return (ushort)r;
}
// 2-term split: RTZ hi + RNE residual (rep error ~2^-17 rel)
__device__ __forceinline__ void split2(float v, ushort& s0, ushort& s1) {
  union { float f; unsigned u; } c; c.f = v;
  s0 = (ushort)(c.u >> 16);
  union { unsigned u; float f; } h; h.u = c.u & 0xffff0000u;
  s1 = f2b(v - h.f);
}
__device__ __forceinline__ float softplusf(float x) {
  return fmaxf(x, 0.f) + log1pf(expf(-fabsf(x)));
}
__device__ __forceinline__ short4v tr16(unsigned a) {
  short4v d;
  asm volatile("ds_read_b64_tr_b16 %0, %1" : "=v"(d) : "v"(a));
  return d;
}

// ---------------- x -> 2 bf16 split planes (row-major, no transpose) ----------------
__global__ __launch_bounds__(256) void xsplit2_k(const float* __restrict__ x,
                                                 ushort* __restrict__ S0,
                                                 ushort* __restrict__ S1) {
  size_t i = ((size_t)blockIdx.x * 256 + threadIdx.x) * 8;
  float v[8];
  *(float4*)&v[0] = *(const float4*)(x + i);
  *(float4*)&v[4] = *(const float4*)(x + i + 4);
  ushort h0[8], h1[8];
#pragma unroll
  for (int j = 0; j < 8; ++j) split2(v[j], h0[j], h1[j]);
  *(uint4*)(S0 + i) = *(uint4*)h0;
  *(uint4*)(S1 + i) = *(uint4*)h1;
}

// -------- transpose one DxD fp32 matrix -> NP bf16 split planes, transposed (NP=1,2) --------
template <int NP>
__global__ __launch_bounds__(256) void split_transposeN(const float* __restrict__ W,
                                                        ushort* __restrict__ T0,
                                                        ushort* __restrict__ T1) {
  __shared__ float tile[64][68];
  int k0 = blockIdx.x << 6, n0 = blockIdx.y << 6;
  int r = threadIdx.x >> 2, c0 = (threadIdx.x & 3) << 4;
  const float* src = W + (size_t)(k0 + r) * Dd + n0 + c0;
#pragma unroll
  for (int q = 0; q < 4; ++q)
    *(float4*)&tile[r][c0 + 4 * q] = *(const float4*)(src + 4 * q);
  __syncthreads();
  ushort h0[16], h1[16];
#pragma unroll
  for (int i = 0; i < 16; ++i) {
    float v = tile[c0 + i][r];
    if (NP == 1) {
      h0[i] = f2b(v);
    } else {
      // RNE hi + RNE residual: rep err ~2^-18
      ushort a = f2b(v); h0[i] = a; h1[i] = f2b(v - b2f(a));
    }
  }
  size_t o = (size_t)(n0 + r) * Dd + k0 + c0;
  *(uint4*)(T0 + o) = *(uint4*)&h0[0];  *(uint4*)(T0 + o + 8) = *(uint4*)&h0[8];
  if (NP >= 2) { *(uint4*)(T1 + o) = *(uint4*)&h1[0];  *(uint4*)(T1 + o + 8) = *(uint4*)&h1[8]; }
}

// ======== 128x128-tile 3-term GEMM, PRE-SPLIT A (2+2 bf16 planes): Q, K, G ========
__global__ __launch_bounds__(512) void gemm128_pre2(const ushort* __restrict__ A0,
                                                    const ushort* __restrict__ A1,
                                                    const ushort* __restrict__ B0,
                                                    const ushort* __restrict__ B1,
                                                    float* __restrict__ C) {
  const int N = 2048, K = 2048;
  int m0 = blockIdx.y << 7, n0 = blockIdx.x << 7;
  __shared__ ushort As0[8192], As1[8192], Bs0[8192], Bs1[8192];
  int tid = threadIdx.x;
  int row = tid >> 2, c0 = (tid & 3) << 4;
  int sw = row & 7, g0 = c0 >> 3;
  int dst0 = row * 64 + ((g0 ^ sw) << 3);
  int dst1 = row * 64 + (((g0 + 1) ^ sw) << 3);
  const ushort* a0p = A0 + (size_t)(m0 + row) * K + c0;
  const ushort* a1p = A1 + (size_t)(m0 + row) * K + c0;
  const ushort* b0p = B0 + (size_t)(n0 + row) * K + c0;
  const ushort* b1p = B1 + (size_t)(n0 + row) * K + c0;
  int lane = tid & 63, wave = tid >> 6;
  int l16 = lane & 15, quad = lane >> 4;
  int wm = (wave & 1) << 6, wn = (wave >> 1) << 5;
  f32x4 acc[4][2] = {};
  for (int k0 = 0; k0 < K; k0 += 64) {
    uint4 a00 = *(const uint4*)(a0p + k0), a01 = *(const uint4*)(a0p + k0 + 8);
    uint4 a10 = *(const uint4*)(a1p + k0), a11 = *(const uint4*)(a1p + k0 + 8);
    uint4 b00 = *(const uint4*)(b0p + k0), b01 = *(const uint4*)(b0p + k0 + 8);
    uint4 b10 = *(const uint4*)(b1p + k0), b11 = *(const uint4*)(b1p + k0 + 8);
    *(uint4*)&As0[dst0] = a00;  *(uint4*)&As0[dst1] = a01;
    *(uint4*)&As1[dst0] = a10;  *(uint4*)&As1[dst1] = a11;
    *(uint4*)&Bs0[dst0] = b00;  *(uint4*)&Bs0[dst1] = b01;
    *(uint4*)&Bs1[dst0] = b10;  *(uint4*)&Bs1[dst1] = b11;
    __syncthreads();
#pragma unroll
    for (int kk = 0; kk < 2; ++kk) {
      short8 af0[4], af1[4], bf0[2], bf1[2];
#pragma unroll
      for (int mi = 0; mi < 4; ++mi) {
        int rr = wm + (mi << 4) + l16;
        int g = (kk << 2) + quad;
        int idx = rr * 64 + ((g ^ (rr & 7)) << 3);
        af0[mi] = *(const short8*)&As0[idx];
        af1[mi] = *(const short8*)&As1[idx];
      }
#pragma unroll
      for (int nj = 0; nj < 2; ++nj) {
        int rr = wn + (nj << 4) + l16;
        int g = (kk << 2) + quad;
        int idx = rr * 64 + ((g ^ (rr & 7)) << 3);
        bf0[nj] = *(const short8*)&Bs0[idx];
        bf1[nj] = *(const short8*)&Bs1[idx];
      }
#pragma unroll
      for (int mi = 0; mi < 4; ++mi)
#pragma unroll
        for (int nj = 0; nj < 2; ++nj) {
          acc[mi][nj] = __builtin_amdgcn_mfma_f32_16x16x32_bf16(af1[mi], bf0[nj], acc[mi][nj], 0, 0, 0);
          acc[mi][nj] = __builtin_amdgcn_mfma_f32_16x16x32_bf16(af0[mi], bf1[nj], acc[mi][nj], 0, 0, 0);
          acc[mi][nj] = __builtin_amdgcn_mfma_f32_16x16x32_bf16(af0[mi], bf0[nj], acc[mi][nj], 0, 0, 0);
        }
    }
    __syncthreads();
  }
#pragma unroll
  for (int mi = 0; mi < 4; ++mi)
#pragma unroll
    for (int nj = 0; nj < 2; ++nj)
#pragma unroll
      for (int r = 0; r < 4; ++r) {
        int mm = m0 + wm + (mi << 4) + (quad << 2) + r;
        int nn = n0 + wn + (nj << 4) + l16;
        C[(size_t)mm * N + nn] = acc[mi][nj][r];
      }
}

// ======== 128x128-tile 3-term GEMM, fp32 A split in-kernel (2 B planes): P, V ========
template <int BF16OUT>
__global__ __launch_bounds__(512) void gemm128_split2(const float* __restrict__ A,
                                                      const ushort* __restrict__ B0,
                                                      const ushort* __restrict__ B1,
                                                      void* __restrict__ CBase) {
  const int N = 2048, K = 2048;
  int m0 = blockIdx.y << 7, n0 = blockIdx.x << 7;
  __shared__ ushort As0[8192], As1[8192], Bs0[8192], Bs1[8192];
  int tid = threadIdx.x;
  int row = tid >> 2, c0 = (tid & 3) << 4;
  int sw = row & 7, g0 = c0 >> 3;
  int dst0 = row * 64 + ((g0 ^ sw) << 3);
  int dst1 = row * 64 + (((g0 + 1) ^ sw) << 3);
  const float* aptr = A + (size_t)(m0 + row) * K + c0;
  const ushort* b0p = B0 + (size_t)(n0 + row) * K + c0;
  const ushort* b1p = B1 + (size_t)(n0 + row) * K + c0;
  int lane = tid & 63, wave = tid >> 6;
  int l16 = lane & 15, quad = lane >> 4;
  int wm = (wave & 1) << 6, wn = (wave >> 1) << 5;
  f32x4 acc[4][2] = {};
  for (int k0 = 0; k0 < K; k0 += 64) {
    float av[16];
#pragma unroll
    for (int q = 0; q < 4; ++q)
      *(float4*)&av[4 * q] = *(const float4*)(aptr + k0 + 4 * q);
    ushort a0[16], a1[16];
#pragma unroll
    for (int i = 0; i < 16; ++i) split2(av[i], a0[i], a1[i]);
    uint4 b00 = *(const uint4*)(b0p + k0), b01 = *(const uint4*)(b0p + k0 + 8);
    uint4 b10 = *(const uint4*)(b1p + k0), b11 = *(const uint4*)(b1p + k0 + 8);
    *(uint4*)&As0[dst0] = *(uint4*)&a0[0];  *(uint4*)&As0[dst1] = *(uint4*)&a0[8];
    *(uint4*)&As1[dst0] = *(uint4*)&a1[0];  *(uint4*)&As1[dst1] = *(uint4*)&a1[8];
    *(uint4*)&Bs0[dst0] = b00;  *(uint4*)&Bs0[dst1] = b01;
    *(uint4*)&Bs1[dst0] = b10;  *(uint4*)&Bs1[dst1] = b11;
    __syncthreads();
#pragma unroll
    for (int kk = 0; kk < 2; ++kk) {
      short8 af0[4], af1[4], bf0[2], bf1[2];
#pragma unroll
      for (int mi = 0; mi < 4; ++mi) {
        int rr = wm + (mi << 4) + l16;
        int g = (kk << 2) + quad;
        int idx = rr * 64 + ((g ^ (rr & 7)) << 3);
        af0[mi] = *(const short8*)&As0[idx];
        af1[mi] = *(const short8*)&As1[idx];
      }
#pragma unroll
      for (int nj = 0; nj < 2; ++nj) {
        int rr = wn + (nj << 4) + l16;
        int g = (kk << 2) + quad;
        int idx = rr * 64 + ((g ^ (rr & 7)) << 3);
        bf0[nj] = *(const short8*)&Bs0[idx];
        bf1[nj] = *(const short8*)&Bs1[idx];
      }
#pragma unroll
      for (int mi = 0; mi < 4; ++mi)
#pragma unroll
        for (int nj = 0; nj < 2; ++nj) {
          acc[mi][nj] = __builtin_amdgcn_mfma_f32_16x16x32_bf16(af1[mi], bf0[nj], acc[mi][nj], 0, 0, 0);
          acc[mi][nj] = __builtin_amdgcn_mfma_f32_16x16x32_bf16(af0[mi], bf1[nj], acc[mi][nj], 0, 0, 0);
          acc[mi][nj] = __builtin_amdgcn_mfma_f32_16x16x32_bf16(af0[mi], bf0[nj], acc[mi][nj], 0, 0, 0);
        }
    }
    __syncthreads();
  }
#pragma unroll
  for (int mi = 0; mi < 4; ++mi)
#pragma unroll
    for (int nj = 0; nj < 2; ++nj)
#pragma unroll
      for (int r = 0; r < 4; ++r) {
        int mm = m0 + wm + (mi << 4) + (quad << 2) + r;
        int nn = n0 + wn + (nj << 4) + l16;
        float v = acc[mi][nj][r];
        if (BF16OUT)
          ((ushort*)CBase)[(size_t)mm * N + nn] = f2b(v);
        else
          ((float*)CBase)[(size_t)mm * N + nn] = v;
      }
}

// ======== 128x128-tile bf16 x bf16 GEMM (final projection), fp32 out ========
__global__ __launch_bounds__(512) void gemm128_b16(const ushort* __restrict__ A,
                                                   const ushort* __restrict__ Bt,
                                                   float* __restrict__ C) {
  const int N = 2048, K = 2048;
  int m0 = blockIdx.y << 7, n0 = blockIdx.x << 7;
  __shared__ ushort As[8192], Bs[8192];
  int tid = threadIdx.x;
  int row = tid >> 2, c0 = (tid & 3) << 4;
  int sw = row & 7, g0 = c0 >> 3;
  int dst0 = row * 64 + ((g0 ^ sw) << 3);
  int dst1 = row * 64 + (((g0 + 1) ^ sw) << 3);
  const ushort* aptr = A + (size_t)(m0 + row) * K + c0;
  const ushort* bptr = Bt + (size_t)(n0 + row) * K + c0;
  int lane = tid & 63, wave = tid >> 6;
  int l16 = lane & 15, quad = lane >> 4;
  int wm = (wave & 1) << 6, wn = (wave >> 1) << 5;
  f32x4 acc[4][2] = {};
  for (int k0 = 0; k0 < K; k0 += 64) {
    uint4 av0 = *(const uint4*)(aptr + k0), av1 = *(const uint4*)(aptr + k0 + 8);
    uint4 bv0 = *(const uint4*)(bptr + k0), bv1 = *(const uint4*)(bptr + k0 + 8);
    *(uint4*)&As[dst0] = av0;  *(uint4*)&As[dst1] = av1;
    *(uint4*)&Bs[dst0] = bv0;  *(uint4*)&Bs[dst1] = bv1;
    __syncthreads();
#pragma unroll
    for (int kk = 0; kk < 2; ++kk) {
      short8 af[4], bf[2];
#pragma unroll
      for (int mi = 0; mi < 4; ++mi) {
        int rr = wm + (mi << 4) + l16;
        int g = (kk << 2) + quad;
        af[mi] = *(const short8*)&As[rr * 64 + ((g ^ (rr & 7)) << 3)];
      }
#pragma unroll
      for (int nj = 0; nj < 2; ++nj) {
        int rr = wn + (nj << 4) + l16;
        int g = (kk << 2) + quad;
        bf[nj] = *(const short8*)&Bs[rr * 64 + ((g ^ (rr & 7)) << 3)];
      }
#pragma unroll
      for (int mi = 0; mi < 4; ++mi)
#pragma unroll
        for (int nj = 0; nj < 2; ++nj)
          acc[mi][nj] = __builtin_amdgcn_mfma_f32_16x16x32_bf16(af[mi], bf[nj], acc[mi][nj], 0, 0, 0);
    }
    __syncthreads();
  }
#pragma unroll
  for (int mi = 0; mi < 4; ++mi)
#pragma unroll
    for (int nj = 0; nj < 2; ++nj)
#pragma unroll
      for (int r = 0; r < 4; ++r) {
        int mm = m0 + wm + (mi << 4) + (quad << 2) + r;
        int nn = n0 + wn + (nj << 4) + l16;
        C[(size_t)mm * N + nn] = acc[mi][nj][r];
      }
}

// ---------------- clock pre-activation: x @ W_clock (2048x16), fp32 ----------------
__global__ __launch_bounds__(64) void wclock_k(const float* __restrict__ x,
                                               const float* __restrict__ Wc,
                                               float* __restrict__ out) {
  int m = blockIdx.x, lane = threadIdx.x;
  const float* xr = x + (size_t)m * Dd;
  float acc[16];
#pragma unroll
  for (int h = 0; h < 16; ++h) acc[h] = 0.f;
  for (int k = lane; k < Dd; k += 64) {
    float xv = xr[k];
    const float* wr = Wc + k * 16;
#pragma unroll
    for (int h = 0; h < 16; ++h) acc[h] += xv * wr[h];
  }
#pragma unroll
  for (int h = 0; h < 16; ++h) {
#pragma unroll
    for (int off = 32; off; off >>= 1) acc[h] += __shfl_down(acc[h], off);
  }
  if (lane == 0) {
    float* o = out + (size_t)m * 16;
#pragma unroll
    for (int h = 0; h < 16; ++h) o[h] = acc[h];
  }
}

// -------- per-chunk max of p over 256-t chunks (4-way split + LDS reduce) --------
__global__ __launch_bounds__(512) void pmaxchunk_k(const float* __restrict__ Pf,
                                                   const float* __restrict__ cpre,
                                                   float* __restrict__ pmaxc) {
  __shared__ float red[4][128];
  int bh = blockIdx.x, ch = blockIdx.y;
  int d = threadIdx.x & 127, qtr = threadIdx.x >> 7;
  int b = bh >> 4, h = bh & 15;
  float mx = -1e30f;
  int t0 = (ch << 8) + (qtr << 6);
  for (int t = t0; t < t0 + 64; ++t) {
    float pr = Pf[((size_t)(b * Tt + t)) * Dd + h * 128 + d];
    float c = softplusf(cpre[(b * Tt + t) * Hh + h]) + 1e-6f;
    mx = fmaxf(mx, pr + logf(c));
  }
  red[qtr][d] = mx;
  __syncthreads();
  if (qtr == 0)
    pmaxc[(size_t)(bh * 8 + ch) * 128 + d] =
        fmaxf(fmaxf(red[0][d], red[1][d]), fmaxf(red[2][d], red[3][d]));
}

// ======== blocked scan, stage 1: elementwise (rope, pe, gj, clock) + per-32t chunk sums ========
__global__ __launch_bounds__(128) void scan_ew_k(float* planes,
                                                 const float* __restrict__ cpre,
                                                 const float* __restrict__ pmaxc,
                                                 float* __restrict__ clockv,
                                                 float* __restrict__ sum_pe,
                                                 float* __restrict__ sum_gj,
                                                 float* __restrict__ sum_ck) {
  int ch = blockIdx.x, bh = blockIdx.y;
  int b = bh >> 4, h = bh & 15, d = threadIdx.x;
  float* Qf = planes;
  float* Kf = planes + (size_t)MD;
  float* Gf = planes + 2 * (size_t)MD;
  float* Pf = planes + 3 * (size_t)MD;
  float invf = (float)exp(-((double)((d & 63) * 2) / 128.0) * log(10000.0));
  float pmax = -1e30f;
#pragma unroll
  for (int c = 0; c < 8; ++c) pmax = fmaxf(pmax, pmaxc[(size_t)(bh * 8 + c) * 128 + d]);
  float s_pe = 0.f, s_gj = 0.f, s_ck = 0.f;
  int t0 = ch << 5;
#pragma unroll 4
  for (int i = 0; i < 32; ++i) {
    int t = t0 + i;
    size_t off = ((size_t)(b * Tt + t)) * Dd + h * 128 + d;
    float qv = Qf[off], kv = Kf[off], pv = Pf[off], gv = Gf[off];
    float clock = softplusf(cpre[(b * Tt + t) * Hh + h]) + 1e-6f;
    float ang = (float)t * invf;
    float c_ = cosf(ang), s_ = sinf(ang);
    float qp = __shfl_xor(qv, 1);
    float kp = __shfl_xor(kv, 1);
    float qrot = (d & 1) ? qp : -qp;
    float krot = (d & 1) ? kp : -kp;
    float qr = qv * c_ + qrot * s_;
    float kr = kv * c_ + krot * s_;
    float pe = expf(pv + logf(clock) - pmax);
    s_pe += pe;
    float gj = -softplusf(gv) * clock;
    s_gj += gj;
    Qf[off] = qr;
    Kf[off] = kr;
    Gf[off] = gj;     // gj for now; scan_apply_k turns it into e
    Pf[off] = pe;
    if (d == 0) {
      clockv[bh * Tt + t] = clock;
      s_ck += clock;
    }
  }
  size_t so = (size_t)(bh * 64 + ch) * 128 + d;
  sum_pe[so] = s_pe;
  sum_gj[so] = s_gj;
  if (d == 0) sum_ck[bh * 64 + ch] = s_ck;
}

// ======== blocked scan, stage 2: exclusive scan of chunk sums (pcs_cp falls out directly) ========
__global__ __launch_bounds__(128) void scan_off_k(const float* __restrict__ sum_pe,
                                                  const float* __restrict__ sum_gj,
                                                  const float* __restrict__ sum_ck,
                                                  float* __restrict__ pcs_cp,
                                                  float* __restrict__ goff,
                                                  float* __restrict__ coff) {
  int bh = blockIdx.x, d = threadIdx.x;
  float ppe = 0.f, pgj = 0.f, pck = 0.f;
  for (int c = 0; c < 64; ++c) {
    size_t o = (size_t)(bh * 64 + c) * 128 + d;
    pcs_cp[o] = ppe;
    goff[o] = pgj;
    ppe += sum_pe[o];
    pgj += sum_gj[o];
    if (d == 0) { coff[bh * 64 + c] = pck; pck += sum_ck[bh * 64 + c]; }
  }
}

// ======== blocked scan, stage 3: within-chunk gcs -> e (Gf), and ccsv ========
__global__ __launch_bounds__(128) void scan_apply_k(float* planes,
                                                    const float* __restrict__ goff,
                                                    const float* __restrict__ coff,
                                                    const float* __restrict__ clockv,
                                                    float* __restrict__ ccsv) {
  int ch = blockIdx.x, bh = blockIdx.y;
  int b = bh >> 4, h = bh & 15, d = threadIdx.x;
  float* Gf = planes + 2 * (size_t)MD;
  float g = goff[(size_t)(bh * 64 + ch) * 128 + d];
  float ccs = (d == 0) ? coff[bh * 64 + ch] : 0.f;
  int t0 = ch << 5;
#pragma unroll 4
  for (int i = 0; i < 32; ++i) {
    int t = t0 + i;
    size_t off = ((size_t)(b * Tt + t)) * Dd + h * 128 + d;
    float gj = Gf[off];
    g += gj;
    float e = expf(fminf(fmaxf(g, -50.f), 40.f));
    Gf[off] = e;
    if (d == 0) {
      ccs += clockv[bh * Tt + t];
      ccsv[bh * Tt + t] = ccs;
    }
  }
}

// ---------------- MFMA flash attention: 128 q-rows/block, 8 waves x 16 rows ----------------
__global__ __launch_bounds__(512, 2) void attn_mfma_k(const float* __restrict__ planes,
                                                      const ushort* __restrict__ Vb,
                                                      const float* __restrict__ clockv,
                                                      const float* __restrict__ ccsv,
                                                      const float* __restrict__ pcs_cp,
                                                      ushort* __restrict__ attnout) {
  __shared__ float smemf[18432];            // 72 KB -> 2 blocks/CU, 16 waves/CU
  ushort* Khi = (ushort*)smemf;             // [32 keys][384 dims] swizzled  @0      (24576 B)
  ushort* Klo = Khi + 12288;                //                              @24576  (24576 B)
  ushort* Vsm = Khi + 24576;                // [32 keys][128 dims] 4x16-subtiled @49152 (8192 B)
  unsigned* Pu = (unsigned*)(smemf + 14336);// 8 waves x [16 rows][32 keys] u32 @57344 (16384 B)
  float* pcsL = smemf;                      // phase alias @0: [64][128] f32 (32 KB)
  ushort* qscr = (ushort*)(smemf + 8192);   // phase alias @32768: 4 x 8 KB

  int tid = threadIdx.x;
  int lane = tid & 63, wave = tid >> 6;     // wave 0..7
  int l15 = lane & 15, qd = lane >> 4;
  int qt0 = blockIdx.x << 7;                // 128 q rows per block
  int bh = blockIdx.y, b = bh >> 4, h = bh & 15;
  const float* Qf = planes;
  const float* Kf = planes + (size_t)MD;
  const float* Ef = planes + 2 * (size_t)MD;
  const float* Pe = planes + 3 * (size_t)MD;
  size_t pbase = ((size_t)b * Tt) * Dd + h * 128;

  // ---- Q prep in 2 rounds: rows 0..63 (waves 0..3), rows 64..127 (waves 4..7) ----
  short8 qh[12], ql[12];
  int wl = wave & 3;
  int rloc = lane >> 2;                     // 0..15, row within wave tile
  {
    ushort* sh = qscr + (wl << 12);         // [16][128] hi ushort (4 KB)
    ushort* sl = sh + 2048;                 // lo (4 KB)
#pragma unroll
    for (int rd = 0; rd < 2; ++rd) {
      // phase A: pcs replay for this round's 64 rows (256 threads; chunk==32 rows)
      if (tid < 256) {
        int d = tid & 127, seg = tid >> 7;
        int rbase = (rd << 6) + (seg << 5);
        float pcs = pcs_cp[((size_t)bh * 64 + (qt0 >> 5) + (rd << 1) + seg) * 128 + d];
        for (int i = 0; i < 32; ++i) {
          pcs += Pe[pbase + (size_t)(qt0 + rbase + i) * Dd + d];
          pcsL[((seg << 5) + i) * 128 + d] = pcs;
        }
      }
      __syncthreads();
      int part = ((wave >> 2) == rd);
      int grow = qt0 + (rd << 6) + (wl << 4) + rloc;
      float ccsr = __builtin_amdgcn_rcpf(ccsv[bh * Tt + grow]);
      size_t goffq = pbase + (size_t)grow * Dd;
#pragma unroll
      for (int cd = 0; cd < 3; ++cd) {
        __syncthreads();
        if (part) {
#pragma unroll
          for (int j = 0; j < 4; ++j) {
            int d0 = ((lane & 3) << 5) + (j << 3);   // 8 dims
            float qv[8], mv[8];
            *(float4*)&qv[0] = *(const float4*)(Qf + goffq + d0);
            *(float4*)&qv[4] = *(const float4*)(Qf + goffq + d0 + 4);
            if (cd == 0) {
              *(float4*)&mv[0] = *(const float4*)&pcsL[((wl << 4) + rloc) * 128 + d0];
              *(float4*)&mv[4] = *(const float4*)&pcsL[((wl << 4) + rloc) * 128 + d0 + 4];
#pragma unroll
              for (int i = 0; i < 8; ++i) qv[i] = qv[i] * __builtin_amdgcn_rcpf(mv[i] + 1e-8f);
            } else if (cd == 1) {
              *(float4*)&mv[0] = *(const float4*)(Ef + goffq + d0);
              *(float4*)&mv[4] = *(const float4*)(Ef + goffq + d0 + 4);
#pragma unroll
              for (int i = 0; i < 8; ++i) qv[i] = qv[i] * mv[i];
            } else {
#pragma unroll
              for (int i = 0; i < 8; ++i) qv[i] = qv[i] * ccsr;
            }
            ushort hi8[8], lo8[8];
#pragma unroll
            for (int i = 0; i < 8; ++i) {
              ushort a = f2b(qv[i]); hi8[i] = a; lo8[i] = f2b(qv[i] - b2f(a));
            }
            int g = ((lane & 3) << 2) + j;          // dim group 0..15
            int phys = (g & 8) | ((g ^ rloc) & 7);
            *(uint4*)&sh[rloc * 128 + (phys << 3)] = *(uint4*)hi8;
            *(uint4*)&sl[rloc * 128 + (phys << 3)] = *(uint4*)lo8;
          }
        }
        __syncthreads();
        if (part) {
#pragma unroll
          for (int ksl = 0; ksl < 4; ++ksl) {
            int g = (ksl << 2) + qd;
            int phys = (g & 8) | ((g ^ l15) & 7);
            qh[(cd << 2) + ksl] = *(const short8*)&sh[l15 * 128 + (phys << 3)];
            ql[(cd << 2) + ksl] = *(const short8*)&sl[l15 * 128 + (phys << 3)];
          }
        }
      }
      __syncthreads();                      // pcsL/qscr reuse (and Khi alias) safe
    }
  }

  // ---- main loop over 64 key-tiles of 32 ----
  float mi4[4], li4[4];
  f32x4 acc_pv[8] = {};
#pragma unroll
  for (int r = 0; r < 4; ++r) { mi4[r] = -1e30f; li4[r] = 0.f; }
  const float scl = 0.05103103630798287f;   // 1/sqrt(384)
  const ushort* vbase = Vb + pbase;
  unsigned* PuW = Pu + (wave << 9);         // per-wave 2 KB
  unsigned VsmA = (unsigned)(size_t)Vsm;    // LDS byte address (low 32 bits of flat)
  int kk = tid >> 4;                        // key 0..31 (staging role)
  int kdb = tid & 15;                       // 8-dim block (staging role)

  for (int st = 0; st < 64; ++st) {
    int s0 = st << 5;
    __syncthreads();                        // all reads of K/V tile (st-1) done
    // ---- stage K (3 cat slots, RTZ-hi + exact-residual-lo split) + V tile (4x16 subtiles) ----
    {
      size_t roff = pbase + (size_t)(s0 + kk) * Dd + (kdb << 3);
      float ck = clockv[bh * Tt + s0 + kk];
      float kv[8], pev[8], ev[8];
      *(float4*)&kv[0] = *(const float4*)(Kf + roff);
      *(float4*)&kv[4] = *(const float4*)(Kf + roff + 4);
      *(float4*)&pev[0] = *(const float4*)(Pe + roff);
      *(float4*)&pev[4] = *(const float4*)(Pe + roff + 4);
      *(float4*)&ev[0] = *(const float4*)(Ef + roff);
      *(float4*)&ev[4] = *(const float4*)(Ef + roff + 4);
#pragma unroll
      for (int slot = 0; slot < 3; ++slot) {
        float val[8];
        if (slot == 0) {
#pragma unroll
          for (int i = 0; i < 8; ++i) val[i] = kv[i] * pev[i];
        } else if (slot == 1) {
#pragma unroll
          for (int i = 0; i < 8; ++i) val[i] = kv[i] * __builtin_amdgcn_rcpf(ev[i] + 1e-8f);
        } else {
#pragma unroll
          for (int i = 0; i < 8; ++i) val[i] = kv[i] * ck;
        }
        unsigned ub[8], ul[8];
#pragma unroll
        for (int i = 0; i < 8; ++i) {
          union { float f; unsigned u; } c; c.f = val[i];
          ub[i] = c.u;
          union { unsigned u; float f; } hm; hm.u = c.u & 0xffff0000u;
          union { float f; unsigned u; } lr; lr.f = val[i] - hm.f;
          ul[i] = lr.u;
        }
        uint4 hi4, lo4;
        hi4.x = (ub[0] >> 16) | (ub[1] & 0xffff0000u);
        hi4.y = (ub[2] >> 16) | (ub[3] & 0xffff0000u);
        hi4.z = (ub[4] >> 16) | (ub[5] & 0xffff0000u);
        hi4.w = (ub[6] >> 16) | (ub[7] & 0xffff0000u);
        lo4.x = (ul[0] >> 16) | (ul[1] & 0xffff0000u);
        lo4.y = (ul[2] >> 16) | (ul[3] & 0xffff0000u);
        lo4.z = (ul[4] >> 16) | (ul[5] & 0xffff0000u);
        lo4.w = (ul[6] >> 16) | (ul[7] & 0xffff0000u);
        int g = (slot << 4) + kdb;
        int phys = (g & ~7) | ((g ^ kk) & 7);
        *(uint4*)&Khi[kk * 384 + (phys << 3)] = hi4;
        *(uint4*)&Klo[kk * 384 + (phys << 3)] = lo4;
      }
      // V: subtile layout
      const ushort* vsrc = vbase + (size_t)(s0 + kk) * Dd + (kdb << 3);
      int vbyte = ((kdb >> 1) << 10) + (((kk >> 2) & 1) << 9) + ((kk >> 3) << 7) +
                  ((kk & 3) << 5) + ((kdb & 1) << 4);
      *(uint4*)((char*)Vsm + vbyte) = *(const uint4*)vsrc;
    }
    __syncthreads();
    // ---- QK^T: 2-term split-bf16 MFMA (3 terms, smallest first) ----
    f32x4 acc0 = {}, acc1 = {};
    __builtin_amdgcn_s_setprio(1);
#pragma unroll
    for (int ks = 0; ks < 12; ++ks) {
      int g = (ks << 2) + qd;
      int p0i = (g & ~7) | ((g ^ l15) & 7);
      int p1i = (g & ~7) | ((g ^ (16 + l15)) & 7);
      short8 b0h = *(const short8*)&Khi[l15 * 384 + (p0i << 3)];
      short8 b0l = *(const short8*)&Klo[l15 * 384 + (p0i << 3)];
      short8 b1h = *(const short8*)&Khi[(16 + l15) * 384 + (p1i << 3)];
      short8 b1l = *(const short8*)&Klo[(16 + l15) * 384 + (p1i << 3)];
      acc0 = __builtin_amdgcn_mfma_f32_16x16x32_bf16(ql[ks], b0h, acc0, 0, 0, 0);
      acc0 = __builtin_amdgcn_mfma_f32_16x16x32_bf16(qh[ks], b0l, acc0, 0, 0, 0);
      acc0 = __builtin_amdgcn_mfma_f32_16x16x32_bf16(qh[ks], b0h, acc0, 0, 0, 0);
      acc1 = __builtin_amdgcn_mfma_f32_16x16x32_bf16(ql[ks], b1h, acc1, 0, 0, 0);
      acc1 = __builtin_amdgcn_mfma_f32_16x16x32_bf16(qh[ks], b1l, acc1, 0, 0, 0);
      acc1 = __builtin_amdgcn_mfma_f32_16x16x32_bf16(qh[ks], b1h, acc1, 0, 0, 0);
    }
    __builtin_amdgcn_s_setprio(0);
    // ---- online softmax; P -> Pu (hi/lo packed) ----
#pragma unroll
    for (int r = 0; r < 4; ++r) {
      float sa = acc0[r] * scl, sb = acc1[r] * scl;
      float mx = fmaxf(sa, sb);
#pragma unroll
      for (int m = 1; m < 16; m <<= 1) mx = fmaxf(mx, __shfl_xor(mx, m));
      float mn = fmaxf(mi4[r], mx);
      float al = expf(mi4[r] - mn);
      float p0 = expf(sa - mn), p1 = expf(sb - mn);
      float rs = p0 + p1;
#pragma unroll
      for (int m = 1; m < 16; m <<= 1) rs += __shfl_xor(rs, m);
      li4[r] = li4[r] * al + rs;
      mi4[r] = mn;
#pragma unroll
      for (int n0 = 0; n0 < 8; ++n0) acc_pv[n0][r] *= al;
      int R = (qd << 2) + r;
      {
        union { float f; unsigned u; } c0, c1; c0.f = p0; c1.f = p1;
        union { unsigned u; float f; } m0_, m1_;
        m0_.u = c0.u & 0xffff0000u; m1_.u = c1.u & 0xffff0000u;
        union { float f; unsigned u; } d0_, d1_;
        d0_.f = p0 - m0_.f; d1_.f = p1 - m1_.f;
        unsigned u0 = (c0.u >> 16) | (d0_.u & 0xffff0000u);
        unsigned u1 = (c1.u >> 16) | (d1_.u & 0xffff0000u);
        int r7 = R & 7;
        char* pb = (char*)PuW + (R << 7) + ((l15 & 3) << 2);
        *(unsigned*)(pb + (((l15 >> 2) ^ r7) << 4)) = u0;
        *(unsigned*)(pb + ((((l15 >> 2) + 4) ^ r7) << 4)) = u1;
      }
    }
    // ---- PV via MFMA ----
    {
      unsigned pw[8];
      {
        const char* pb = (const char*)PuW + l15 * 128;
        uint4 w0 = *(const uint4*)(pb + ((((qd << 1)) ^ (l15 & 7)) << 4));
        uint4 w1 = *(const uint4*)(pb + ((((qd << 1) | 1) ^ (l15 & 7)) << 4));
        pw[0] = w0.x; pw[1] = w0.y; pw[2] = w0.z; pw[3] = w0.w;
        pw[4] = w1.x; pw[5] = w1.y; pw[6] = w1.z; pw[7] = w1.w;
      }
      union { unsigned u[4]; short8 s; } uph, upl;
#pragma unroll
      for (int i = 0; i < 4; ++i) {
        uph.u[i] = (pw[2 * i] & 0xffffu) | (pw[2 * i + 1] << 16);
        upl.u[i] = (pw[2 * i] >> 16) | (pw[2 * i + 1] & 0xffff0000u);
      }
      short4v tv[16];
#pragma unroll
      for (int n0 = 0; n0 < 8; ++n0) {
        unsigned a0 = VsmA + (n0 << 10) + (lane << 3);
        tv[2 * n0] = tr16(a0);
        tv[2 * n0 + 1] = tr16(a0 + 512);
      }
      asm volatile("s_waitcnt lgkmcnt(0)" ::: "memory");
      __builtin_amdgcn_sched_barrier(0);
      __builtin_amdgcn_s_setprio(1);
#pragma unroll
      for (int n0 = 0; n0 < 8; ++n0) {
        short8 bv = __builtin_shufflevector(tv[2 * n0], tv[2 * n0 + 1], 0, 1, 2, 3, 4, 5, 6, 7);
        acc_pv[n0] = __builtin_amdgcn_mfma_f32_16x16x32_bf16(uph.s, bv, acc_pv[n0], 0, 0, 0);
        acc_pv[n0] = __builtin_amdgcn_mfma_f32_16x16x32_bf16(upl.s, bv, acc_pv[n0], 0, 0, 0);
      }
      __builtin_amdgcn_s_setprio(0);
    }
  }
  // ---- epilogue: normalize, bf16 out ----
#pragma unroll
  for (int r = 0; r < 4; ++r) {
    float inv = 1.f / li4[r];
    int trow = qt0 + (wave << 4) + (qd << 2) + r;
    ushort* orow = attnout + ((size_t)(b * Tt + trow)) * Dd + h * 128 + l15;
#pragma unroll
    for (int n0 = 0; n0 < 8; ++n0)
      orow[n0 << 4] = f2b(acc_pv[n0][r] * inv);
  }
}

extern "C" void kernel_launch(void* const* d_in, const int* in_sizes, int n_in,
                              void* d_out, int out_size, void* d_ws, size_t ws_size,
                              hipStream_t stream) {
  const float* x = (const float*)d_in[0];
  const float* Wq = (const float*)d_in[1];
  const float* Wk = (const float*)d_in[2];
  const float* Wv = (const float*)d_in[3];
  const float* Wg = (const float*)d_in[4];
  const float* Wp = (const float*)d_in[5];
  const float* Wclk = (const float*)d_in[6];
  const float* Wc = (const float*)d_in[7];

  // ---- workspace layout (~178 MiB) ----
  float* planes = (float*)d_ws;                       // 4 * MD fp32: qr | kr | e | pe
  float* Aq = planes;
  float* Bk = planes + (size_t)MD;
  float* Ce = planes + 2 * (size_t)MD;
  float* Dp = planes + 3 * (size_t)MD;
  ushort* Vb = (ushort*)(planes + 4 * (size_t)MD);    // MD bf16
  float* cpre = (float*)(Vb + (size_t)MD);            // 65536
  float* clockv = cpre + 65536;                       // 65536
  float* ccsv = clockv + 65536;                       // 65536
  float* pmaxc = ccsv + 65536;                        // 32768
  float* pcs_cp = pmaxc + 32768;                      // 32*64*128 = 262144
  ushort* Wt0 = (ushort*)(pcs_cp + 262144);           // 3 x Dd*Dd bf16 (projection phase)
  ushort* Wt1 = Wt0 + (size_t)Dd * Dd;
  ushort* Wt2 = Wt1 + (size_t)Dd * Dd;
  ushort* attnout = Wt0;                              // reuse Wt region (dead after projections)
  ushort* WcT0 = (ushort*)Ce;                         // post-attention: reuse e-plane for Wc^T
  // x-split planes (2 x 16.8 MB) live entirely in the Dp region (32 MB fp32) — dead until the
  // P projection, which reads x directly and runs after all xs consumers (stream-ordered).
  ushort* xs0 = (ushort*)Dp;                          // MD bf16
  ushort* xs1 = xs0 + (size_t)MD;                     // MD bf16
  // scan temporaries live in the Wt2 region
  float* sum_pe = (float*)Wt2;                        // 262144
  float* sum_gj = sum_pe + 262144;                    // 262144
  float* goff_  = sum_gj + 262144;                    // 262144
  float* sum_ck = goff_ + 262144;                     // 2048
  float* coff_  = sum_ck + 2048;                      // 2048

  size_t needed = (size_t)((char*)(Wt2 + (size_t)Dd * Dd) - (char*)d_ws);
  if (ws_size < needed) return;  // diagnostic: absmax ~= 4.69 => ws too small

  dim3 tg(Dd / 64, Dd / 64);
  dim3 g128(Dd / 128, Mm / 128);

  // x split planes (once, 2-plane)
  xsplit2_k<<<dim3(MD / 8 / 256), 256, 0, stream>>>(x, xs0, xs1);

  // Q, K, G projections: 3-term, 128x128 tile (pre-split A).
  // G is safe at 3-term: gcs is clipped to [-50,40], e enters scores only as the ratio
  // e_i/e_j (errors cancel to ~1e-4 in the exponent), and the 1e-8 guard zeroes the
  // deep-clipped region's contribution.
  split_transposeN<2><<<tg, 256, 0, stream>>>(Wq, Wt0, Wt1);
  gemm128_pre2<<<g128, 512, 0, stream>>>(xs0, xs1, Wt0, Wt1, Aq);
  split_transposeN<2><<<tg, 256, 0, stream>>>(Wk, Wt0, Wt1);
  gemm128_pre2<<<g128, 512, 0, stream>>>(xs0, xs1, Wt0, Wt1, Bk);
  split_transposeN<2><<<tg, 256, 0, stream>>>(Wg, Wt0, Wt1);
  gemm128_pre2<<<g128, 512, 0, stream>>>(xs0, xs1, Wt0, Wt1, Ce);
  // P, V projections: 3-term 128x128, direct-x path (P overwrites the now-dead xs planes)
  split_transposeN<2><<<tg, 256, 0, stream>>>(Wp, Wt0, Wt1);
  gemm128_split2<0><<<g128, 512, 0, stream>>>(x, Wt0, Wt1, (void*)Dp);
  split_transposeN<2><<<tg, 256, 0, stream>>>(Wv, Wt0, Wt1);
  gemm128_split2<1><<<g128, 512, 0, stream>>>(x, Wt0, Wt1, (void*)Vb);

  // clock pre-activation, chunked p_max
  wclock_k<<<dim3(Mm), dim3(64), 0, stream>>>(x, Wclk, cpre);
  pmaxchunk_k<<<dim3(Bb * Hh, 8), dim3(512), 0, stream>>>(Dp, cpre, pmaxc);

  // blocked scan
  scan_ew_k<<<dim3(64, Bb * Hh), dim3(128), 0, stream>>>(planes, cpre, pmaxc, clockv,
                                                         sum_pe, sum_gj, sum_ck);
  scan_off_k<<<dim3(Bb * Hh), dim3(128), 0, stream>>>(sum_pe, sum_gj, sum_ck,
                                                      pcs_cp, goff_, coff_);
  scan_apply_k<<<dim3(64, Bb * Hh), dim3(128), 0, stream>>>(planes, goff_, coff_, clockv, ccsv);

  // MFMA flash attention -> attnout
  attn_mfma_k<<<dim3(Tt / 128, Bb * Hh), dim3(512), 0, stream>>>(planes, Vb, clockv, ccsv, pcs_cp, attnout);

  // Wc^T (1 plane), then final GEMM (128x128) -> fp32 d_out
  split_transposeN<1><<<tg, 256, 0, stream>>>(Wc, WcT0, nullptr);
  gemm128_b16<<<g128, 512, 0, stream>>>(attnout, WcT0, (float*)d_out);
}